// Round 8
// baseline (479.879 us; speedup 1.0000x reference)
//
#include <hip/hip_runtime.h>
#include <cstdint>
#include <cstddef>

#define N_NODES 20000
#define N_EDGES 400000
#define NBLK 79  // ceil(20000/256)
#define MPAD 20128  // N_NODES rounded up to 128-row tiles

typedef __attribute__((ext_vector_type(8))) short bf16x8;
typedef __attribute__((ext_vector_type(4))) float f32x4;
typedef __attribute__((ext_vector_type(2))) int i32x2;

// ---------- bf16 helpers (manual, bit-exact) ----------
__device__ __forceinline__ float bf2f(unsigned short u) {
    return __uint_as_float(((unsigned int)u) << 16);
}
__device__ __forceinline__ unsigned short f2bf(float f) {
    unsigned int x = __float_as_uint(f);
    unsigned int lsb = (x >> 16) & 1u;
    x += 0x7fffu + lsb;  // round-to-nearest-even
    return (unsigned short)(x >> 16);
}

// ---------- flag-aware loads for harness float tensors (bf16 or fp32) ----------
__device__ __forceinline__ float ldF(const void* p, size_t i, bool bf) {
    return bf ? bf2f(((const unsigned short*)p)[i]) : ((const float*)p)[i];
}

// ---------- async global->LDS 16B copy ----------
__device__ __forceinline__ void gl2lds16(const unsigned short* g, unsigned short* l) {
    __builtin_amdgcn_global_load_lds(
        (const __attribute__((address_space(1))) void*)g,
        (__attribute__((address_space(3))) void*)l, 16, 0, 0);
}

// ---------- dtype + int64 detection (one wave, lane-parallel) ----------
__global__ void k_detect(const unsigned int* __restrict__ xw, const int* __restrict__ raw,
                         int* __restrict__ flag) {
    int lane = threadIdx.x;
    int cnt = 0, nz = 0;
    for (int i = lane; i < 256; i += 64) {
        unsigned short lo = (unsigned short)(xw[i] & 0xffffu);
        int e = (lo >> 7) & 0xff;
        if (e >= 110 && e <= 135) cnt++;
    }
    for (int i = 2 * lane + 1; i < 512; i += 128)
        if (raw[i] != 0) nz++;
#pragma unroll
    for (int off = 32; off > 0; off >>= 1) {
        cnt += __shfl_down(cnt, off);
        nz  += __shfl_down(nz, off);
    }
    if (lane == 0) {
        flag[0] = (cnt >= 128) ? 1 : 0;  // 1 = float tensors are bf16
        flag[1] = (nz == 0) ? 1 : 0;     // 1 = edge_index is raw int64
    }
}

// ---------- degree + counts (reads raw edge_index directly) ----------
__global__ void k_canon_deg(const int* __restrict__ raw, const void* __restrict__ ew,
                            const int* __restrict__ flagp,
                            float* __restrict__ deg, int* __restrict__ counts) {
    bool bf = (flagp[0] != 0);
    int is64 = flagp[1];
    int e = blockIdx.x * blockDim.x + threadIdx.x;
    if (e >= N_EDGES) return;
    int d;
    if (is64) d = raw[2 * (N_EDGES + e)];
    else      d = raw[N_EDGES + e];
    atomicAdd(&deg[d], ldF(ew, e, bf));
    atomicAdd(&counts[d], 1);
}

// ---------- pass 1: per-block count sums + fused dinv/selfnorm ----------
__global__ __launch_bounds__(256) void k_part(const int* __restrict__ counts,
                                              const float* __restrict__ deg,
                                              float* __restrict__ dinv,
                                              float* __restrict__ selfnorm,
                                              int* __restrict__ bsum) {
    __shared__ int s[256];
    int t = threadIdx.x;
    int i = blockIdx.x * 256 + t;
    int c = (i < N_NODES) ? counts[i] : 0;
    if (i < N_NODES) {
        float d = deg[i] + 1.0f;
        float r = rsqrtf(d);
        dinv[i] = r;
        selfnorm[i] = r * r;
    }
    s[t] = c;
    __syncthreads();
    for (int off = 128; off > 0; off >>= 1) {
        if (t < off) s[t] += s[t + off];
        __syncthreads();
    }
    if (t == 0) bsum[blockIdx.x] = s[0];
}

// ---------- pass 2: exclusive scan of 79 block sums (1 tiny block) ----------
__global__ void k_scanb(const int* __restrict__ bsum, int* __restrict__ bofs,
                        int* __restrict__ rowptr) {
    __shared__ int s[128];
    int t = threadIdx.x;
    int v = (t < NBLK) ? bsum[t] : 0;
    s[t] = v;
    __syncthreads();
    for (int off = 1; off < 128; off <<= 1) {
        int u = (t >= off) ? s[t - off] : 0;
        __syncthreads();
        s[t] += u;
        __syncthreads();
    }
    if (t < NBLK) bofs[t] = s[t] - v;  // exclusive
    if (t == NBLK - 1) rowptr[N_NODES] = s[t];
}

// ---------- pass 3: intra-block scan + block offset -> rowptr ----------
__global__ __launch_bounds__(256) void k_row(const int* __restrict__ counts,
                                             const int* __restrict__ bofs,
                                             int* __restrict__ rowptr) {
    __shared__ int s[256];
    int t = threadIdx.x;
    int b = blockIdx.x;
    int i = b * 256 + t;
    int c = (i < N_NODES) ? counts[i] : 0;
    s[t] = c;
    __syncthreads();
    for (int off = 1; off < 256; off <<= 1) {
        int u = (t >= off) ? s[t - off] : 0;
        __syncthreads();
        s[t] += u;
        __syncthreads();
    }
    if (i < N_NODES) rowptr[i] = bofs[b] + s[t] - c;
}

// ---------- scatter edges into CSR-by-dst: packed (src, norm) pairs ----------
__global__ void k_csr(const int* __restrict__ raw, const void* __restrict__ ew,
                      const int* __restrict__ flagp,
                      const float* __restrict__ dinv, const int* __restrict__ rowptr,
                      int* __restrict__ fill, int* __restrict__ csr_pair) {
    bool bf = (flagp[0] != 0);
    int is64 = flagp[1];
    int e = blockIdx.x * blockDim.x + threadIdx.x;
    if (e >= N_EDGES) return;
    int s, d;
    if (is64) { s = raw[2 * e]; d = raw[2 * (N_EDGES + e)]; }
    else      { s = raw[e];     d = raw[N_EDGES + e]; }
    int p = rowptr[d] + atomicAdd(&fill[d], 1);
    float nrm = dinv[s] * ldF(ew, e, bf) * dinv[d];
    i32x2 pv;
    pv.x = s;
    pv.y = __float_as_int(nrm);
    *(i32x2*)(csr_pair + 2 * (size_t)p) = pv;
}

// ---------- merged prep: cast x -> bf16 (fp32 input only) | pack weights | biases ----------
__global__ __launch_bounds__(256) void k_prep(const void* __restrict__ x,
                                              const void* __restrict__ W1,
                                              const void* __restrict__ W2,
                                              const void* __restrict__ W3,
                                              const void* __restrict__ W4,
                                              const void* __restrict__ b1,
                                              const void* __restrict__ b2,
                                              const void* __restrict__ b3,
                                              const void* __restrict__ b4,
                                              const void* __restrict__ W5,
                                              const int* __restrict__ flagp,
                                              unsigned short* __restrict__ P,
                                              unsigned short* __restrict__ Wp,
                                              float* __restrict__ biasf) {
    bool bf = (*flagp != 0);
    int b = blockIdx.x;
    int t = threadIdx.x;
    if (b < 10000) {
        if (bf) return;  // bf16 input: layer-1 GEMM reads x directly, no copy needed
        int i = b * 256 + t;  // < 2,560,000 exactly
        float4 v = ((const float4*)x)[i];
        unsigned int lo = (unsigned int)f2bf(v.x) | ((unsigned int)f2bf(v.y) << 16);
        unsigned int hi = (unsigned int)f2bf(v.z) | ((unsigned int)f2bf(v.w) << 16);
        ((uint2*)P)[i] = make_uint2(lo, hi);
    } else if (b < 10448) {
        int gidx = (b - 10000) * 256 + t;
        if (gidx >= 114688) return;
        const void* W;
        int idx = gidx, N, nbl;
        if (gidx < 32768)      { W = W1; N = 512; nbl = 5; }
        else if (gidx < 65536) { W = W2; N = 512; nbl = 5; idx -= 32768; }
        else if (gidx < 98304) { W = W3; N = 512; nbl = 5; idx -= 65536; }
        else                   { W = W4; N = 256; nbl = 4; idx -= 98304; }
        int lane = idx & 63;
        int blk = idx >> 6;
        int nb = blk & ((1 << nbl) - 1);
        int kb = blk >> nbl;
        int n = (nb << 4) + (lane & 15);
        int kbase = (kb << 5) + ((lane >> 4) << 3);
        unsigned short o[8];
#pragma unroll
        for (int j = 0; j < 8; ++j)
            o[j] = f2bf(ldF(W, (size_t)(kbase + j) * N + n, bf));
        *(uint4*)(&Wp[(size_t)gidx * 8]) = *(const uint4*)o;
    } else {
        int i = (b - 10448) * 256 + t;
        if (i >= 2304) return;
        if (i < 2048) {
            int L = i >> 9, r = i & 511;
            if (L == 3 && r >= 256) return;
            const void* bb = (L == 0) ? b1 : (L == 1) ? b2 : (L == 2) ? b3 : b4;
            biasf[i] = ldF(bb, r, bf);
        } else {
            biasf[i] = ldF(W5, i - 2048, bf);  // fp32 W5 at biasf[2048..2303]
        }
    }
}

// ---------- MFMA bf16 GEMM, 128x128 tile, BK=64: C = A * Wp(packed) ----------
// A = (flag ? Aalt : Abase): lets layer 1 read the harness x tensor directly
// when it is already bf16. Row index clamped to M-1 in staging (x is not padded).
__global__ __launch_bounds__(256) void k_gemm_mfma(const unsigned short* __restrict__ Abase,
                                                   const unsigned short* __restrict__ Aalt,
                                                   const int* __restrict__ flagp,
                                                   const unsigned short* __restrict__ Bp,
                                                   unsigned short* __restrict__ C,
                                                   int M, int K, int N) {
    const int AP = 72;  // A-tile row stride (64 + 8 pad) shorts -> 2-way-max banks
    __shared__ __align__(16) unsigned short As[128 * AP];  // 18432 B
    __shared__ __align__(16) unsigned short Bs[2 * 8 * 512];  // 16384 B
    const unsigned short* A = (*flagp != 0) ? Aalt : Abase;
    int tid = threadIdx.x;
    int lane = tid & 63;
    int wave = tid >> 6;
    int wr = wave >> 1, wc = wave & 1;
    int row0 = blockIdx.x * 128;
    int col0 = blockIdx.y * 128;
    int nbt = N >> 4;
    int q = lane >> 4;
    int mm = lane & 15;

    f32x4 acc[4][4] = {};

    for (int kb2 = 0; kb2 < (K >> 6); ++kb2) {
        const unsigned short* breg0 = Bp + (((size_t)(2 * kb2) * nbt + (col0 >> 4)) << 9);
        const unsigned short* breg1 = Bp + (((size_t)(2 * kb2 + 1) * nbt + (col0 >> 4)) << 9);
        gl2lds16(breg0 + (size_t)tid * 8, &Bs[(size_t)tid * 8]);
        gl2lds16(breg0 + (size_t)(tid + 256) * 8, &Bs[(size_t)(tid + 256) * 8]);
        gl2lds16(breg1 + (size_t)tid * 8, &Bs[4096 + (size_t)tid * 8]);
        gl2lds16(breg1 + (size_t)(tid + 256) * 8, &Bs[4096 + (size_t)(tid + 256) * 8]);
#pragma unroll
        for (int i = 0; i < 4; ++i) {
            int c = tid + i * 256;
            int row = c >> 3, kq = c & 7;
            int grow = min(row0 + row, M - 1);  // clamp: A may be the unpadded x
            uint4 v = *(const uint4*)(&A[(size_t)grow * K + (kb2 << 6) + (kq << 3)]);
            *(uint4*)(&As[row * AP + (kq << 3)]) = v;
        }
        __syncthreads();
#pragma unroll
        for (int kk = 0; kk < 2; ++kk) {
            bf16x8 af[4], bfr[4];
#pragma unroll
            for (int mb = 0; mb < 4; ++mb)
                af[mb] = *(const bf16x8*)(&As[(wr * 64 + mb * 16 + mm) * AP + kk * 32 + q * 8]);
#pragma unroll
            for (int nb = 0; nb < 4; ++nb)
                bfr[nb] = *(const bf16x8*)(&Bs[kk * 4096 + ((wc * 4 + nb) * 64 + lane) * 8]);
#pragma unroll
            for (int mb = 0; mb < 4; ++mb)
#pragma unroll
                for (int nb = 0; nb < 4; ++nb)
                    acc[mb][nb] = __builtin_amdgcn_mfma_f32_16x16x32_bf16(
                        af[mb], bfr[nb], acc[mb][nb], 0, 0, 0);
        }
        __syncthreads();
    }
#pragma unroll
    for (int mb = 0; mb < 4; ++mb) {
#pragma unroll
        for (int r = 0; r < 4; ++r) {
            int grow = row0 + wr * 64 + mb * 16 + q * 4 + r;
            if (grow < M) {
#pragma unroll
                for (int nb = 0; nb < 4; ++nb) {
                    int gcol = col0 + wc * 64 + nb * 16 + mm;
                    C[(size_t)grow * N + gcol] = f2bf(acc[mb][nb][r]);
                }
            }
        }
    }
}

// ---------- row-load + fma helpers for the gather ----------
template <int W>
__device__ __forceinline__ void ldrow(const unsigned short* h, size_t row, int F, int lane,
                                      unsigned int* u) {
    const unsigned int* p = (const unsigned int*)(h + row * F) + lane * W;
    if constexpr (W == 4) {
        uint4 v = *(const uint4*)p; u[0] = v.x; u[1] = v.y; u[2] = v.z; u[3] = v.w;
    } else {
        uint2 v = *(const uint2*)p; u[0] = v.x; u[1] = v.y;
    }
}
template <int W>
__device__ __forceinline__ void fmarow(const unsigned int* u, float w, float* acc) {
#pragma unroll
    for (int k = 0; k < W; ++k) {
        acc[2 * k]     = fmaf(bf2f((unsigned short)(u[k] & 0xffffu)), w, acc[2 * k]);
        acc[2 * k + 1] = fmaf(bf2f((unsigned short)(u[k] >> 16)),     w, acc[2 * k + 1]);
    }
}

// ---------- 8-chunk XCD-pinned aggregate, 2 nodes/wave (F=512) ----------
// chunk = blockIdx & 7 -> 64-feat slice = 2.56 MB/XCD, fully L2-resident
// (round-2/3: FETCH 23-26 MB at 8 chunks). Instruction structure is the proven
// round-7 one: no shuffles, cached broadcast pair loads, 8-edge unroll.
// Wave = two 32-lane halves, one node each (32 dwords = 64 feats = chunk slice).
// Cost: exec-mask waste ~|deg_a-deg_b|/max ~12%. No cross-half reduce.
__global__ __launch_bounds__(64) void k_agg_w(const unsigned short* __restrict__ h,
                                              const int* __restrict__ rowptr,
                                              const int* __restrict__ csr_pair,
                                              const float* __restrict__ selfnorm,
                                              const float* __restrict__ biasf,
                                              unsigned short* __restrict__ out) {
    constexpr int F = 512;
    int tid = threadIdx.x;
    int half = tid >> 5;  // 0 or 1: which node this lane serves
    int col = tid & 31;   // dword column within the 64-feat chunk slice
    int chunk = blockIdx.x & 7;
    int node = (blockIdx.x >> 3) * 2 + half;  // 20000 even: always in-bounds
    int e0 = rowptr[node], e1 = rowptr[node + 1];
    float sn = selfnorm[node];
    const unsigned short* hb = h + chunk * 64 + col * 2;

    float a0, a1;
    {
        unsigned int u = *(const unsigned int*)(hb + (size_t)node * F);
        a0 = sn * bf2f((unsigned short)(u & 0xffffu));
        a1 = sn * bf2f((unsigned short)(u >> 16));
    }
    const i32x2* pairs = (const i32x2*)csr_pair;
    int j = e0;
    for (; j + 7 < e1; j += 8) {
        i32x2 p0 = pairs[j],     p1 = pairs[j + 1], p2 = pairs[j + 2], p3 = pairs[j + 3];
        i32x2 p4 = pairs[j + 4], p5 = pairs[j + 5], p6 = pairs[j + 6], p7 = pairs[j + 7];
        unsigned int u0 = *(const unsigned int*)(hb + (size_t)p0.x * F);
        unsigned int u1 = *(const unsigned int*)(hb + (size_t)p1.x * F);
        unsigned int u2 = *(const unsigned int*)(hb + (size_t)p2.x * F);
        unsigned int u3 = *(const unsigned int*)(hb + (size_t)p3.x * F);
        unsigned int u4 = *(const unsigned int*)(hb + (size_t)p4.x * F);
        unsigned int u5 = *(const unsigned int*)(hb + (size_t)p5.x * F);
        unsigned int u6 = *(const unsigned int*)(hb + (size_t)p6.x * F);
        unsigned int u7 = *(const unsigned int*)(hb + (size_t)p7.x * F);
        float w0 = __int_as_float(p0.y), w1 = __int_as_float(p1.y);
        float w2 = __int_as_float(p2.y), w3 = __int_as_float(p3.y);
        float w4 = __int_as_float(p4.y), w5 = __int_as_float(p5.y);
        float w6 = __int_as_float(p6.y), w7 = __int_as_float(p7.y);
        a0 = fmaf(bf2f((unsigned short)(u0 & 0xffffu)), w0, a0);
        a1 = fmaf(bf2f((unsigned short)(u0 >> 16)),     w0, a1);
        a0 = fmaf(bf2f((unsigned short)(u1 & 0xffffu)), w1, a0);
        a1 = fmaf(bf2f((unsigned short)(u1 >> 16)),     w1, a1);
        a0 = fmaf(bf2f((unsigned short)(u2 & 0xffffu)), w2, a0);
        a1 = fmaf(bf2f((unsigned short)(u2 >> 16)),     w2, a1);
        a0 = fmaf(bf2f((unsigned short)(u3 & 0xffffu)), w3, a0);
        a1 = fmaf(bf2f((unsigned short)(u3 >> 16)),     w3, a1);
        a0 = fmaf(bf2f((unsigned short)(u4 & 0xffffu)), w4, a0);
        a1 = fmaf(bf2f((unsigned short)(u4 >> 16)),     w4, a1);
        a0 = fmaf(bf2f((unsigned short)(u5 & 0xffffu)), w5, a0);
        a1 = fmaf(bf2f((unsigned short)(u5 >> 16)),     w5, a1);
        a0 = fmaf(bf2f((unsigned short)(u6 & 0xffffu)), w6, a0);
        a1 = fmaf(bf2f((unsigned short)(u6 >> 16)),     w6, a1);
        a0 = fmaf(bf2f((unsigned short)(u7 & 0xffffu)), w7, a0);
        a1 = fmaf(bf2f((unsigned short)(u7 >> 16)),     w7, a1);
    }
    for (; j + 3 < e1; j += 4) {
        i32x2 p0 = pairs[j], p1 = pairs[j + 1], p2 = pairs[j + 2], p3 = pairs[j + 3];
        unsigned int u0 = *(const unsigned int*)(hb + (size_t)p0.x * F);
        unsigned int u1 = *(const unsigned int*)(hb + (size_t)p1.x * F);
        unsigned int u2 = *(const unsigned int*)(hb + (size_t)p2.x * F);
        unsigned int u3 = *(const unsigned int*)(hb + (size_t)p3.x * F);
        float w0 = __int_as_float(p0.y), w1 = __int_as_float(p1.y);
        float w2 = __int_as_float(p2.y), w3 = __int_as_float(p3.y);
        a0 = fmaf(bf2f((unsigned short)(u0 & 0xffffu)), w0, a0);
        a1 = fmaf(bf2f((unsigned short)(u0 >> 16)),     w0, a1);
        a0 = fmaf(bf2f((unsigned short)(u1 & 0xffffu)), w1, a0);
        a1 = fmaf(bf2f((unsigned short)(u1 >> 16)),     w1, a1);
        a0 = fmaf(bf2f((unsigned short)(u2 & 0xffffu)), w2, a0);
        a1 = fmaf(bf2f((unsigned short)(u2 >> 16)),     w2, a1);
        a0 = fmaf(bf2f((unsigned short)(u3 & 0xffffu)), w3, a0);
        a1 = fmaf(bf2f((unsigned short)(u3 >> 16)),     w3, a1);
    }
    for (; j < e1; ++j) {
        i32x2 p0 = pairs[j];
        unsigned int u0 = *(const unsigned int*)(hb + (size_t)p0.x * F);
        float w0 = __int_as_float(p0.y);
        a0 = fmaf(bf2f((unsigned short)(u0 & 0xffffu)), w0, a0);
        a1 = fmaf(bf2f((unsigned short)(u0 >> 16)),     w0, a1);
    }
    {
        const float* bp = biasf + chunk * 64 + col * 2;
        a0 = fmaxf(a0 + bp[0], 0.f);
        a1 = fmaxf(a1 + bp[1], 0.f);
        unsigned int o = (unsigned int)f2bf(a0) | ((unsigned int)f2bf(a1) << 16);
        *(unsigned int*)(out + (size_t)node * F + chunk * 64 + col * 2) = o;
    }
}

// ---------- L4 agg fused with L5 GEMV: h5[node] = dot(relu(agg+b4), W5) ----------
// Unchanged round-6 structure (single dispatch; keep attribution clean).
__global__ __launch_bounds__(64) void k_agg_fuse(const unsigned short* __restrict__ h,
                                                 const int* __restrict__ rowptr,
                                                 const int* __restrict__ csr_pair,
                                                 const float* __restrict__ selfnorm,
                                                 const float* __restrict__ biasf,
                                                 const float* __restrict__ w5f,
                                                 float* __restrict__ h5) {
    constexpr int F = 256, FPL = 4, W = 2;
    int lane = threadIdx.x;
    int node = blockIdx.x;
    int e0 = rowptr[node], e1 = rowptr[node + 1];
    float sn = selfnorm[node];

    float acc[FPL];
    {
        unsigned int u[W];
        ldrow<W>(h, (size_t)node, F, lane, u);
#pragma unroll
        for (int k = 0; k < W; ++k) {
            acc[2 * k]     = sn * bf2f((unsigned short)(u[k] & 0xffffu));
            acc[2 * k + 1] = sn * bf2f((unsigned short)(u[k] >> 16));
        }
    }
    const i32x2* pairs = (const i32x2*)csr_pair;
    int j = e0;
    for (; j + 7 < e1; j += 8) {
        i32x2 p0 = pairs[j],     p1 = pairs[j + 1], p2 = pairs[j + 2], p3 = pairs[j + 3];
        i32x2 p4 = pairs[j + 4], p5 = pairs[j + 5], p6 = pairs[j + 6], p7 = pairs[j + 7];
        unsigned int u0[W], u1[W], u2[W], u3[W], u4[W], u5[W], u6[W], u7[W];
        ldrow<W>(h, (size_t)p0.x, F, lane, u0);
        ldrow<W>(h, (size_t)p1.x, F, lane, u1);
        ldrow<W>(h, (size_t)p2.x, F, lane, u2);
        ldrow<W>(h, (size_t)p3.x, F, lane, u3);
        ldrow<W>(h, (size_t)p4.x, F, lane, u4);
        ldrow<W>(h, (size_t)p5.x, F, lane, u5);
        ldrow<W>(h, (size_t)p6.x, F, lane, u6);
        ldrow<W>(h, (size_t)p7.x, F, lane, u7);
        fmarow<W>(u0, __int_as_float(p0.y), acc);
        fmarow<W>(u1, __int_as_float(p1.y), acc);
        fmarow<W>(u2, __int_as_float(p2.y), acc);
        fmarow<W>(u3, __int_as_float(p3.y), acc);
        fmarow<W>(u4, __int_as_float(p4.y), acc);
        fmarow<W>(u5, __int_as_float(p5.y), acc);
        fmarow<W>(u6, __int_as_float(p6.y), acc);
        fmarow<W>(u7, __int_as_float(p7.y), acc);
    }
    for (; j + 3 < e1; j += 4) {
        i32x2 p0 = pairs[j], p1 = pairs[j + 1], p2 = pairs[j + 2], p3 = pairs[j + 3];
        unsigned int u0[W], u1[W], u2[W], u3[W];
        ldrow<W>(h, (size_t)p0.x, F, lane, u0);
        ldrow<W>(h, (size_t)p1.x, F, lane, u1);
        ldrow<W>(h, (size_t)p2.x, F, lane, u2);
        ldrow<W>(h, (size_t)p3.x, F, lane, u3);
        fmarow<W>(u0, __int_as_float(p0.y), acc);
        fmarow<W>(u1, __int_as_float(p1.y), acc);
        fmarow<W>(u2, __int_as_float(p2.y), acc);
        fmarow<W>(u3, __int_as_float(p3.y), acc);
    }
    for (; j < e1; ++j) {
        i32x2 p0 = pairs[j];
        unsigned int u0[W];
        ldrow<W>(h, (size_t)p0.x, F, lane, u0);
        fmarow<W>(u0, __int_as_float(p0.y), acc);
    }
    const float* bp = biasf + lane * FPL;
    const float* wp = w5f + lane * FPL;
    float partial = 0.f;
#pragma unroll
    for (int k = 0; k < FPL; ++k)
        partial += fmaxf(acc[k] + bp[k], 0.f) * wp[k];
#pragma unroll
    for (int off = 32; off > 0; off >>= 1)
        partial += __shfl_xor(partial, off);
    if (lane == 0) h5[node] = partial;
}

// ---------- final scalar aggregate, write output in harness dtype ----------
__global__ void k_final(const float* __restrict__ h5, const int* __restrict__ rowptr,
                        const int* __restrict__ csr_pair,
                        const float* __restrict__ selfnorm,
                        const void* __restrict__ b5, const int* __restrict__ flagp,
                        void* __restrict__ out) {
    bool bf = (*flagp != 0);
    int i = blockIdx.x * blockDim.x + threadIdx.x;
    if (i >= N_NODES) return;
    float acc = selfnorm[i] * h5[i];
    int e0 = rowptr[i], e1 = rowptr[i + 1];
    for (int j = e0; j < e1; ++j) {
        int s = csr_pair[2 * (size_t)j];
        float w = __int_as_float(csr_pair[2 * (size_t)j + 1]);
        acc += w * h5[s];
    }
    acc += ldF(b5, 0, bf);
    if (bf) ((unsigned short*)out)[i] = f2bf(acc);
    else    ((float*)out)[i] = acc;
}

extern "C" void kernel_launch(void* const* d_in, const int* in_sizes, int n_in,
                              void* d_out, int out_size, void* d_ws, size_t ws_size,
                              hipStream_t stream) {
    const void* x  = d_in[0];
    const int*  ei = (const int*)d_in[1];
    const void* ea = d_in[2];
    const void* W1 = d_in[3];
    const void* b1 = d_in[4];
    const void* W2 = d_in[5];
    const void* b2 = d_in[6];
    const void* W3 = d_in[7];
    const void* b3 = d_in[8];
    const void* W4 = d_in[9];
    const void* b4 = d_in[10];
    const void* W5 = d_in[11];
    const void* b5 = d_in[12];

    char* ws = (char*)d_ws;
    size_t off = 0;
    auto take = [&](size_t bytes) -> void* {
        off = (off + 255) & ~(size_t)255;
        void* p = ws + off;
        off += bytes;
        return p;
    };
    int*   flagp    = (int*)take(2 * sizeof(int));
    float* deg      = (float*)take(N_NODES * sizeof(float));
    int*   counts   = (int*)take(N_NODES * sizeof(int));
    int*   fill     = (int*)take(N_NODES * sizeof(int));
    size_t zspan    = (size_t)((char*)(fill + N_NODES) - (char*)deg);
    float* dinv     = (float*)take(N_NODES * sizeof(float));
    float* selfnorm = (float*)take(N_NODES * sizeof(float));
    float* h5       = (float*)take(N_NODES * sizeof(float));
    float* biasf    = (float*)take(2304 * sizeof(float));  // 4x512 biases + 256 W5
    int*   bsum     = (int*)take(128 * sizeof(int));
    int*   bofs     = (int*)take(128 * sizeof(int));
    int*   rowptr   = (int*)take((N_NODES + 1) * sizeof(int));
    int*   csr_pair = (int*)take((size_t)N_EDGES * 2 * sizeof(int));  // (src, normbits)
    unsigned short* Wp = (unsigned short*)take((size_t)114688 * 8 * sizeof(unsigned short));
    unsigned short* P  = (unsigned short*)take((size_t)MPAD * 512 * sizeof(unsigned short));
    unsigned short* H  = (unsigned short*)take((size_t)MPAD * 512 * sizeof(unsigned short));

    (void)hipMemsetAsync(deg, 0, zspan, stream);

    const int EB = (N_EDGES + 255) / 256;
    const int NB = (N_NODES + 255) / 256;  // 79 == NBLK
    const int AGW = (N_NODES / 2) * 8;  // 80000: 10000 node-pairs x 8 chunks

    k_detect<<<1, 64, 0, stream>>>((const unsigned int*)x, ei, flagp);
    k_canon_deg<<<EB, 256, 0, stream>>>(ei, ea, flagp, deg, counts);
    k_part<<<NB, 256, 0, stream>>>(counts, deg, dinv, selfnorm, bsum);
    k_scanb<<<1, 128, 0, stream>>>(bsum, bofs, rowptr);
    k_row<<<NB, 256, 0, stream>>>(counts, bofs, rowptr);
    k_csr<<<EB, 256, 0, stream>>>(ei, ea, flagp, dinv, rowptr, fill, csr_pair);

    k_prep<<<10457, 256, 0, stream>>>(x, W1, W2, W3, W4, b1, b2, b3, b4, W5, flagp,
                                      P, Wp, biasf);

    const int MB128 = (N_NODES + 127) / 128;  // 157

    k_gemm_mfma<<<dim3(MB128, 4), 256, 0, stream>>>(P, (const unsigned short*)x, flagp,
                                                    Wp, H, N_NODES, 512, 512);
    k_agg_w<<<AGW, 64, 0, stream>>>(H, rowptr, csr_pair, selfnorm, biasf, P);
    k_gemm_mfma<<<dim3(MB128, 4), 256, 0, stream>>>(P, P, flagp,
                                                    Wp + (size_t)32768 * 8, H,
                                                    N_NODES, 512, 512);
    k_agg_w<<<AGW, 64, 0, stream>>>(H, rowptr, csr_pair, selfnorm, biasf + 512, P);
    k_gemm_mfma<<<dim3(MB128, 4), 256, 0, stream>>>(P, P, flagp,
                                                    Wp + (size_t)65536 * 8, H,
                                                    N_NODES, 512, 512);
    k_agg_w<<<AGW, 64, 0, stream>>>(H, rowptr, csr_pair, selfnorm, biasf + 1024, P);
    k_gemm_mfma<<<dim3(MB128, 2), 256, 0, stream>>>(P, P, flagp,
                                                    Wp + (size_t)98304 * 8, H,
                                                    N_NODES, 512, 256);
    k_agg_fuse<<<N_NODES, 64, 0, stream>>>(H, rowptr, csr_pair, selfnorm,
                                           biasf + 1536, biasf + 2048, h5);

    k_final<<<NB, 256, 0, stream>>>(h5, rowptr, csr_pair, selfnorm, b5, flagp,
                                    d_out);
}

// Round 9
// 476.979 us; speedup vs baseline: 1.0061x; 1.0061x over previous
//
#include <hip/hip_runtime.h>
#include <cstdint>
#include <cstddef>

#define N_NODES 20000
#define N_EDGES 400000
#define NBLK 79  // ceil(20000/256)
#define MPAD 20128  // N_NODES rounded up to 128-row tiles

typedef __attribute__((ext_vector_type(8))) short bf16x8;
typedef __attribute__((ext_vector_type(4))) float f32x4;
typedef __attribute__((ext_vector_type(2))) int i32x2;

// ---------- bf16 helpers (manual, bit-exact) ----------
__device__ __forceinline__ float bf2f(unsigned short u) {
    return __uint_as_float(((unsigned int)u) << 16);
}
__device__ __forceinline__ unsigned short f2bf(float f) {
    unsigned int x = __float_as_uint(f);
    unsigned int lsb = (x >> 16) & 1u;
    x += 0x7fffu + lsb;  // round-to-nearest-even
    return (unsigned short)(x >> 16);
}

// ---------- flag-aware loads for harness float tensors (bf16 or fp32) ----------
__device__ __forceinline__ float ldF(const void* p, size_t i, bool bf) {
    return bf ? bf2f(((const unsigned short*)p)[i]) : ((const float*)p)[i];
}

// ---------- async global->LDS 16B copy ----------
__device__ __forceinline__ void gl2lds16(const unsigned short* g, unsigned short* l) {
    __builtin_amdgcn_global_load_lds(
        (const __attribute__((address_space(1))) void*)g,
        (__attribute__((address_space(3))) void*)l, 16, 0, 0);
}

// ---------- dtype + int64 detection (one wave, lane-parallel) ----------
__global__ void k_detect(const unsigned int* __restrict__ xw, const int* __restrict__ raw,
                         int* __restrict__ flag) {
    int lane = threadIdx.x;
    int cnt = 0, nz = 0;
    for (int i = lane; i < 256; i += 64) {
        unsigned short lo = (unsigned short)(xw[i] & 0xffffu);
        int e = (lo >> 7) & 0xff;
        if (e >= 110 && e <= 135) cnt++;
    }
    for (int i = 2 * lane + 1; i < 512; i += 128)
        if (raw[i] != 0) nz++;
#pragma unroll
    for (int off = 32; off > 0; off >>= 1) {
        cnt += __shfl_down(cnt, off);
        nz  += __shfl_down(nz, off);
    }
    if (lane == 0) {
        flag[0] = (cnt >= 128) ? 1 : 0;  // 1 = float tensors are bf16
        flag[1] = (nz == 0) ? 1 : 0;     // 1 = edge_index is raw int64
    }
}

// ---------- degree + counts (reads raw edge_index directly) ----------
__global__ void k_canon_deg(const int* __restrict__ raw, const void* __restrict__ ew,
                            const int* __restrict__ flagp,
                            float* __restrict__ deg, int* __restrict__ counts) {
    bool bf = (flagp[0] != 0);
    int is64 = flagp[1];
    int e = blockIdx.x * blockDim.x + threadIdx.x;
    if (e >= N_EDGES) return;
    int d;
    if (is64) d = raw[2 * (N_EDGES + e)];
    else      d = raw[N_EDGES + e];
    atomicAdd(&deg[d], ldF(ew, e, bf));
    atomicAdd(&counts[d], 1);
}

// ---------- pass 1: per-block count sums + fused dinv/selfnorm ----------
__global__ __launch_bounds__(256) void k_part(const int* __restrict__ counts,
                                              const float* __restrict__ deg,
                                              float* __restrict__ dinv,
                                              float* __restrict__ selfnorm,
                                              int* __restrict__ bsum) {
    __shared__ int s[256];
    int t = threadIdx.x;
    int i = blockIdx.x * 256 + t;
    int c = (i < N_NODES) ? counts[i] : 0;
    if (i < N_NODES) {
        float d = deg[i] + 1.0f;
        float r = rsqrtf(d);
        dinv[i] = r;
        selfnorm[i] = r * r;
    }
    s[t] = c;
    __syncthreads();
    for (int off = 128; off > 0; off >>= 1) {
        if (t < off) s[t] += s[t + off];
        __syncthreads();
    }
    if (t == 0) bsum[blockIdx.x] = s[0];
}

// ---------- pass 2: exclusive scan of 79 block sums (1 tiny block) ----------
__global__ void k_scanb(const int* __restrict__ bsum, int* __restrict__ bofs,
                        int* __restrict__ rowptr) {
    __shared__ int s[128];
    int t = threadIdx.x;
    int v = (t < NBLK) ? bsum[t] : 0;
    s[t] = v;
    __syncthreads();
    for (int off = 1; off < 128; off <<= 1) {
        int u = (t >= off) ? s[t - off] : 0;
        __syncthreads();
        s[t] += u;
        __syncthreads();
    }
    if (t < NBLK) bofs[t] = s[t] - v;  // exclusive
    if (t == NBLK - 1) rowptr[N_NODES] = s[t];
}

// ---------- pass 3: intra-block scan + block offset -> rowptr ----------
__global__ __launch_bounds__(256) void k_row(const int* __restrict__ counts,
                                             const int* __restrict__ bofs,
                                             int* __restrict__ rowptr) {
    __shared__ int s[256];
    int t = threadIdx.x;
    int b = blockIdx.x;
    int i = b * 256 + t;
    int c = (i < N_NODES) ? counts[i] : 0;
    s[t] = c;
    __syncthreads();
    for (int off = 1; off < 256; off <<= 1) {
        int u = (t >= off) ? s[t - off] : 0;
        __syncthreads();
        s[t] += u;
        __syncthreads();
    }
    if (i < N_NODES) rowptr[i] = bofs[b] + s[t] - c;
}

// ---------- scatter edges into CSR-by-dst: packed (src, norm) pairs ----------
__global__ void k_csr(const int* __restrict__ raw, const void* __restrict__ ew,
                      const int* __restrict__ flagp,
                      const float* __restrict__ dinv, const int* __restrict__ rowptr,
                      int* __restrict__ fill, int* __restrict__ csr_pair) {
    bool bf = (flagp[0] != 0);
    int is64 = flagp[1];
    int e = blockIdx.x * blockDim.x + threadIdx.x;
    if (e >= N_EDGES) return;
    int s, d;
    if (is64) { s = raw[2 * e]; d = raw[2 * (N_EDGES + e)]; }
    else      { s = raw[e];     d = raw[N_EDGES + e]; }
    int p = rowptr[d] + atomicAdd(&fill[d], 1);
    float nrm = dinv[s] * ldF(ew, e, bf) * dinv[d];
    i32x2 pv;
    pv.x = s;
    pv.y = __float_as_int(nrm);
    *(i32x2*)(csr_pair + 2 * (size_t)p) = pv;
}

// ---------- merged prep: cast x -> bf16 (fp32 input only) | pack weights | biases ----------
__global__ __launch_bounds__(256) void k_prep(const void* __restrict__ x,
                                              const void* __restrict__ W1,
                                              const void* __restrict__ W2,
                                              const void* __restrict__ W3,
                                              const void* __restrict__ W4,
                                              const void* __restrict__ b1,
                                              const void* __restrict__ b2,
                                              const void* __restrict__ b3,
                                              const void* __restrict__ b4,
                                              const void* __restrict__ W5,
                                              const int* __restrict__ flagp,
                                              unsigned short* __restrict__ P,
                                              unsigned short* __restrict__ Wp,
                                              float* __restrict__ biasf) {
    bool bf = (*flagp != 0);
    int b = blockIdx.x;
    int t = threadIdx.x;
    if (b < 10000) {
        if (bf) return;  // bf16 input: layer-1 GEMM reads x directly, no copy needed
        int i = b * 256 + t;  // < 2,560,000 exactly
        float4 v = ((const float4*)x)[i];
        unsigned int lo = (unsigned int)f2bf(v.x) | ((unsigned int)f2bf(v.y) << 16);
        unsigned int hi = (unsigned int)f2bf(v.z) | ((unsigned int)f2bf(v.w) << 16);
        ((uint2*)P)[i] = make_uint2(lo, hi);
    } else if (b < 10448) {
        int gidx = (b - 10000) * 256 + t;
        if (gidx >= 114688) return;
        const void* W;
        int idx = gidx, N, nbl;
        if (gidx < 32768)      { W = W1; N = 512; nbl = 5; }
        else if (gidx < 65536) { W = W2; N = 512; nbl = 5; idx -= 32768; }
        else if (gidx < 98304) { W = W3; N = 512; nbl = 5; idx -= 65536; }
        else                   { W = W4; N = 256; nbl = 4; idx -= 98304; }
        int lane = idx & 63;
        int blk = idx >> 6;
        int nb = blk & ((1 << nbl) - 1);
        int kb = blk >> nbl;
        int n = (nb << 4) + (lane & 15);
        int kbase = (kb << 5) + ((lane >> 4) << 3);
        unsigned short o[8];
#pragma unroll
        for (int j = 0; j < 8; ++j)
            o[j] = f2bf(ldF(W, (size_t)(kbase + j) * N + n, bf));
        *(uint4*)(&Wp[(size_t)gidx * 8]) = *(const uint4*)o;
    } else {
        int i = (b - 10448) * 256 + t;
        if (i >= 2304) return;
        if (i < 2048) {
            int L = i >> 9, r = i & 511;
            if (L == 3 && r >= 256) return;
            const void* bb = (L == 0) ? b1 : (L == 1) ? b2 : (L == 2) ? b3 : b4;
            biasf[i] = ldF(bb, r, bf);
        } else {
            biasf[i] = ldF(W5, i - 2048, bf);  // fp32 W5 at biasf[2048..2303]
        }
    }
}

// ---------- MFMA bf16 GEMM, 128x128 tile, BK=64: C = A * Wp(packed) ----------
// A = (flag ? Aalt : Abase): lets layer 1 read the harness x tensor directly
// when it is already bf16. Row index clamped to M-1 in staging (x is not padded).
__global__ __launch_bounds__(256) void k_gemm_mfma(const unsigned short* __restrict__ Abase,
                                                   const unsigned short* __restrict__ Aalt,
                                                   const int* __restrict__ flagp,
                                                   const unsigned short* __restrict__ Bp,
                                                   unsigned short* __restrict__ C,
                                                   int M, int K, int N) {
    const int AP = 72;  // A-tile row stride (64 + 8 pad) shorts -> 2-way-max banks
    __shared__ __align__(16) unsigned short As[128 * AP];  // 18432 B
    __shared__ __align__(16) unsigned short Bs[2 * 8 * 512];  // 16384 B
    const unsigned short* A = (*flagp != 0) ? Aalt : Abase;
    int tid = threadIdx.x;
    int lane = tid & 63;
    int wave = tid >> 6;
    int wr = wave >> 1, wc = wave & 1;
    int row0 = blockIdx.x * 128;
    int col0 = blockIdx.y * 128;
    int nbt = N >> 4;
    int q = lane >> 4;
    int mm = lane & 15;

    f32x4 acc[4][4] = {};

    for (int kb2 = 0; kb2 < (K >> 6); ++kb2) {
        const unsigned short* breg0 = Bp + (((size_t)(2 * kb2) * nbt + (col0 >> 4)) << 9);
        const unsigned short* breg1 = Bp + (((size_t)(2 * kb2 + 1) * nbt + (col0 >> 4)) << 9);
        gl2lds16(breg0 + (size_t)tid * 8, &Bs[(size_t)tid * 8]);
        gl2lds16(breg0 + (size_t)(tid + 256) * 8, &Bs[(size_t)(tid + 256) * 8]);
        gl2lds16(breg1 + (size_t)tid * 8, &Bs[4096 + (size_t)tid * 8]);
        gl2lds16(breg1 + (size_t)(tid + 256) * 8, &Bs[4096 + (size_t)(tid + 256) * 8]);
#pragma unroll
        for (int i = 0; i < 4; ++i) {
            int c = tid + i * 256;
            int row = c >> 3, kq = c & 7;
            int grow = min(row0 + row, M - 1);  // clamp: A may be the unpadded x
            uint4 v = *(const uint4*)(&A[(size_t)grow * K + (kb2 << 6) + (kq << 3)]);
            *(uint4*)(&As[row * AP + (kq << 3)]) = v;
        }
        __syncthreads();
#pragma unroll
        for (int kk = 0; kk < 2; ++kk) {
            bf16x8 af[4], bfr[4];
#pragma unroll
            for (int mb = 0; mb < 4; ++mb)
                af[mb] = *(const bf16x8*)(&As[(wr * 64 + mb * 16 + mm) * AP + kk * 32 + q * 8]);
#pragma unroll
            for (int nb = 0; nb < 4; ++nb)
                bfr[nb] = *(const bf16x8*)(&Bs[kk * 4096 + ((wc * 4 + nb) * 64 + lane) * 8]);
#pragma unroll
            for (int mb = 0; mb < 4; ++mb)
#pragma unroll
                for (int nb = 0; nb < 4; ++nb)
                    acc[mb][nb] = __builtin_amdgcn_mfma_f32_16x16x32_bf16(
                        af[mb], bfr[nb], acc[mb][nb], 0, 0, 0);
        }
        __syncthreads();
    }
#pragma unroll
    for (int mb = 0; mb < 4; ++mb) {
#pragma unroll
        for (int r = 0; r < 4; ++r) {
            int grow = row0 + wr * 64 + mb * 16 + q * 4 + r;
            if (grow < M) {
#pragma unroll
                for (int nb = 0; nb < 4; ++nb) {
                    int gcol = col0 + wc * 64 + nb * 16 + mm;
                    C[(size_t)grow * N + gcol] = f2bf(acc[mb][nb][r]);
                }
            }
        }
    }
}

// ---------- 8-chunk XCD-pinned aggregate, 2 edges/wave-iter (F=512) ----------
// chunk = blockIdx & 7 == XCD id (round-robin dispatch): 64-feat slice = 2.56 MB,
// fully L2-resident (R8: FETCH 23.7 MB). CSR pair indices stay WAVE-UNIFORM
// (j, j+1, ...) -> compiler emits scalar s_load (R7's win, which R8 lost);
// the two 32-lane halves process edges j and j+1 of the SAME node, selecting
// their pair via v_cndmask. Wave-iters = deg/2 per chunk -> instruction count
// ~= R7's with R8's residency. Cross-half combine: 2x shfl_xor(32) at the end.
__global__ __launch_bounds__(64) void k_agg_w(const unsigned short* __restrict__ h,
                                              const int* __restrict__ rowptr,
                                              const int* __restrict__ csr_pair,
                                              const float* __restrict__ selfnorm,
                                              const float* __restrict__ biasf,
                                              unsigned short* __restrict__ out) {
    constexpr int F = 512;
    int tid = threadIdx.x;
    int half = tid >> 5;  // which edge of each uniform pair this lane serves
    int col = tid & 31;   // dword column within the 64-feat chunk slice
    int chunk = blockIdx.x & 7;
    int node = blockIdx.x >> 3;
    int e0 = rowptr[node], e1 = rowptr[node + 1];
    const unsigned short* hb = h + chunk * 64 + col * 2;

    float a0 = 0.f, a1 = 0.f;
    if (half == 0) {
        float sn = selfnorm[node];
        unsigned int u = *(const unsigned int*)(hb + (size_t)node * F);
        a0 = sn * bf2f((unsigned short)(u & 0xffffu));
        a1 = sn * bf2f((unsigned short)(u >> 16));
    }
    const i32x2* pairs = (const i32x2*)csr_pair;
    int j = e0;
    for (; j + 7 < e1; j += 8) {
        i32x2 q0 = pairs[j],     q1 = pairs[j + 1];
        i32x2 q2 = pairs[j + 2], q3 = pairs[j + 3];
        i32x2 q4 = pairs[j + 4], q5 = pairs[j + 5];
        i32x2 q6 = pairs[j + 6], q7 = pairs[j + 7];
        int   s0 = half ? q1.x : q0.x;
        int   s1 = half ? q3.x : q2.x;
        int   s2 = half ? q5.x : q4.x;
        int   s3 = half ? q7.x : q6.x;
        float w0 = __int_as_float(half ? q1.y : q0.y);
        float w1 = __int_as_float(half ? q3.y : q2.y);
        float w2 = __int_as_float(half ? q5.y : q4.y);
        float w3 = __int_as_float(half ? q7.y : q6.y);
        unsigned int u0 = *(const unsigned int*)(hb + (size_t)s0 * F);
        unsigned int u1 = *(const unsigned int*)(hb + (size_t)s1 * F);
        unsigned int u2 = *(const unsigned int*)(hb + (size_t)s2 * F);
        unsigned int u3 = *(const unsigned int*)(hb + (size_t)s3 * F);
        a0 = fmaf(bf2f((unsigned short)(u0 & 0xffffu)), w0, a0);
        a1 = fmaf(bf2f((unsigned short)(u0 >> 16)),     w0, a1);
        a0 = fmaf(bf2f((unsigned short)(u1 & 0xffffu)), w1, a0);
        a1 = fmaf(bf2f((unsigned short)(u1 >> 16)),     w1, a1);
        a0 = fmaf(bf2f((unsigned short)(u2 & 0xffffu)), w2, a0);
        a1 = fmaf(bf2f((unsigned short)(u2 >> 16)),     w2, a1);
        a0 = fmaf(bf2f((unsigned short)(u3 & 0xffffu)), w3, a0);
        a1 = fmaf(bf2f((unsigned short)(u3 >> 16)),     w3, a1);
    }
    for (; j < e1; j += 2) {
        i32x2 q0 = pairs[j];
        i32x2 q1 = pairs[min(j + 1, e1 - 1)];  // uniform clamp keeps s_load
        bool ok1 = (j + 1) < e1;
        int   s0 = half ? q1.x : q0.x;
        float w0 = half ? (ok1 ? __int_as_float(q1.y) : 0.f) : __int_as_float(q0.y);
        unsigned int u0 = *(const unsigned int*)(hb + (size_t)s0 * F);
        a0 = fmaf(bf2f((unsigned short)(u0 & 0xffffu)), w0, a0);
        a1 = fmaf(bf2f((unsigned short)(u0 >> 16)),     w0, a1);
    }
    a0 += __shfl_xor(a0, 32);
    a1 += __shfl_xor(a1, 32);
    if (half == 0) {
        const float* bp = biasf + chunk * 64 + col * 2;
        a0 = fmaxf(a0 + bp[0], 0.f);
        a1 = fmaxf(a1 + bp[1], 0.f);
        unsigned int o = (unsigned int)f2bf(a0) | ((unsigned int)f2bf(a1) << 16);
        *(unsigned int*)(out + (size_t)node * F + chunk * 64 + col * 2) = o;
    }
}

// ---------- L4 agg fused with L5 GEMV, 4-chunk XCD-pinned (F=256) ----------
// Same 2-edges/wave-iter structure; chunk = blockIdx & 3 (2.56 MB/XCD slice,
// fully resident). Per-chunk partial dot -> atomicAdd into zeroed h5.
__global__ __launch_bounds__(64) void k_agg_fuse(const unsigned short* __restrict__ h,
                                                 const int* __restrict__ rowptr,
                                                 const int* __restrict__ csr_pair,
                                                 const float* __restrict__ selfnorm,
                                                 const float* __restrict__ biasf,
                                                 const float* __restrict__ w5f,
                                                 float* __restrict__ h5) {
    constexpr int F = 256;
    int tid = threadIdx.x;
    int half = tid >> 5;
    int col = tid & 31;
    int chunk = blockIdx.x & 3;
    int node = blockIdx.x >> 2;
    int e0 = rowptr[node], e1 = rowptr[node + 1];
    const unsigned short* hb = h + chunk * 64 + col * 2;

    float a0 = 0.f, a1 = 0.f;
    if (half == 0) {
        float sn = selfnorm[node];
        unsigned int u = *(const unsigned int*)(hb + (size_t)node * F);
        a0 = sn * bf2f((unsigned short)(u & 0xffffu));
        a1 = sn * bf2f((unsigned short)(u >> 16));
    }
    const i32x2* pairs = (const i32x2*)csr_pair;
    int j = e0;
    for (; j + 7 < e1; j += 8) {
        i32x2 q0 = pairs[j],     q1 = pairs[j + 1];
        i32x2 q2 = pairs[j + 2], q3 = pairs[j + 3];
        i32x2 q4 = pairs[j + 4], q5 = pairs[j + 5];
        i32x2 q6 = pairs[j + 6], q7 = pairs[j + 7];
        int   s0 = half ? q1.x : q0.x;
        int   s1 = half ? q3.x : q2.x;
        int   s2 = half ? q5.x : q4.x;
        int   s3 = half ? q7.x : q6.x;
        float w0 = __int_as_float(half ? q1.y : q0.y);
        float w1 = __int_as_float(half ? q3.y : q2.y);
        float w2 = __int_as_float(half ? q5.y : q4.y);
        float w3 = __int_as_float(half ? q7.y : q6.y);
        unsigned int u0 = *(const unsigned int*)(hb + (size_t)s0 * F);
        unsigned int u1 = *(const unsigned int*)(hb + (size_t)s1 * F);
        unsigned int u2 = *(const unsigned int*)(hb + (size_t)s2 * F);
        unsigned int u3 = *(const unsigned int*)(hb + (size_t)s3 * F);
        a0 = fmaf(bf2f((unsigned short)(u0 & 0xffffu)), w0, a0);
        a1 = fmaf(bf2f((unsigned short)(u0 >> 16)),     w0, a1);
        a0 = fmaf(bf2f((unsigned short)(u1 & 0xffffu)), w1, a0);
        a1 = fmaf(bf2f((unsigned short)(u1 >> 16)),     w1, a1);
        a0 = fmaf(bf2f((unsigned short)(u2 & 0xffffu)), w2, a0);
        a1 = fmaf(bf2f((unsigned short)(u2 >> 16)),     w2, a1);
        a0 = fmaf(bf2f((unsigned short)(u3 & 0xffffu)), w3, a0);
        a1 = fmaf(bf2f((unsigned short)(u3 >> 16)),     w3, a1);
    }
    for (; j < e1; j += 2) {
        i32x2 q0 = pairs[j];
        i32x2 q1 = pairs[min(j + 1, e1 - 1)];
        bool ok1 = (j + 1) < e1;
        int   s0 = half ? q1.x : q0.x;
        float w0 = half ? (ok1 ? __int_as_float(q1.y) : 0.f) : __int_as_float(q0.y);
        unsigned int u0 = *(const unsigned int*)(hb + (size_t)s0 * F);
        a0 = fmaf(bf2f((unsigned short)(u0 & 0xffffu)), w0, a0);
        a1 = fmaf(bf2f((unsigned short)(u0 >> 16)),     w0, a1);
    }
    a0 += __shfl_xor(a0, 32);
    a1 += __shfl_xor(a1, 32);
    if (half == 0) {
        const float* bp = biasf + chunk * 64 + col * 2;
        const float* wp = w5f + chunk * 64 + col * 2;
        float partial = fmaxf(a0 + bp[0], 0.f) * wp[0]
                      + fmaxf(a1 + bp[1], 0.f) * wp[1];
        partial += __shfl_xor(partial, 1);
        partial += __shfl_xor(partial, 2);
        partial += __shfl_xor(partial, 4);
        partial += __shfl_xor(partial, 8);
        partial += __shfl_xor(partial, 16);
        if (col == 0) atomicAdd(h5 + node, partial);
    }
}

// ---------- final scalar aggregate, write output in harness dtype ----------
__global__ void k_final(const float* __restrict__ h5, const int* __restrict__ rowptr,
                        const int* __restrict__ csr_pair,
                        const float* __restrict__ selfnorm,
                        const void* __restrict__ b5, const int* __restrict__ flagp,
                        void* __restrict__ out) {
    bool bf = (*flagp != 0);
    int i = blockIdx.x * blockDim.x + threadIdx.x;
    if (i >= N_NODES) return;
    float acc = selfnorm[i] * h5[i];
    int e0 = rowptr[i], e1 = rowptr[i + 1];
    for (int j = e0; j < e1; ++j) {
        int s = csr_pair[2 * (size_t)j];
        float w = __int_as_float(csr_pair[2 * (size_t)j + 1]);
        acc += w * h5[s];
    }
    acc += ldF(b5, 0, bf);
    if (bf) ((unsigned short*)out)[i] = f2bf(acc);
    else    ((float*)out)[i] = acc;
}

extern "C" void kernel_launch(void* const* d_in, const int* in_sizes, int n_in,
                              void* d_out, int out_size, void* d_ws, size_t ws_size,
                              hipStream_t stream) {
    const void* x  = d_in[0];
    const int*  ei = (const int*)d_in[1];
    const void* ea = d_in[2];
    const void* W1 = d_in[3];
    const void* b1 = d_in[4];
    const void* W2 = d_in[5];
    const void* b2 = d_in[6];
    const void* W3 = d_in[7];
    const void* b3 = d_in[8];
    const void* W4 = d_in[9];
    const void* b4 = d_in[10];
    const void* W5 = d_in[11];
    const void* b5 = d_in[12];

    char* ws = (char*)d_ws;
    size_t off = 0;
    auto take = [&](size_t bytes) -> void* {
        off = (off + 255) & ~(size_t)255;
        void* p = ws + off;
        off += bytes;
        return p;
    };
    int*   flagp    = (int*)take(2 * sizeof(int));
    float* deg      = (float*)take(N_NODES * sizeof(float));
    int*   counts   = (int*)take(N_NODES * sizeof(int));
    int*   fill     = (int*)take(N_NODES * sizeof(int));
    float* h5       = (float*)take(N_NODES * sizeof(float));  // zeroed: atomic acc
    size_t zspan    = (size_t)((char*)(h5 + N_NODES) - (char*)deg);
    float* dinv     = (float*)take(N_NODES * sizeof(float));
    float* selfnorm = (float*)take(N_NODES * sizeof(float));
    float* biasf    = (float*)take(2304 * sizeof(float));  // 4x512 biases + 256 W5
    int*   bsum     = (int*)take(128 * sizeof(int));
    int*   bofs     = (int*)take(128 * sizeof(int));
    int*   rowptr   = (int*)take((N_NODES + 1) * sizeof(int));
    int*   csr_pair = (int*)take((size_t)N_EDGES * 2 * sizeof(int));  // (src, normbits)
    unsigned short* Wp = (unsigned short*)take((size_t)114688 * 8 * sizeof(unsigned short));
    unsigned short* P  = (unsigned short*)take((size_t)MPAD * 512 * sizeof(unsigned short));
    unsigned short* H  = (unsigned short*)take((size_t)MPAD * 512 * sizeof(unsigned short));

    (void)hipMemsetAsync(deg, 0, zspan, stream);

    const int EB = (N_EDGES + 255) / 256;
    const int NB = (N_NODES + 255) / 256;  // 79 == NBLK
    const int AGW = N_NODES * 8;  // one (node, chunk) per 64-thread block
    const int AGF = N_NODES * 4;

    k_detect<<<1, 64, 0, stream>>>((const unsigned int*)x, ei, flagp);
    k_canon_deg<<<EB, 256, 0, stream>>>(ei, ea, flagp, deg, counts);
    k_part<<<NB, 256, 0, stream>>>(counts, deg, dinv, selfnorm, bsum);
    k_scanb<<<1, 128, 0, stream>>>(bsum, bofs, rowptr);
    k_row<<<NB, 256, 0, stream>>>(counts, bofs, rowptr);
    k_csr<<<EB, 256, 0, stream>>>(ei, ea, flagp, dinv, rowptr, fill, csr_pair);

    k_prep<<<10457, 256, 0, stream>>>(x, W1, W2, W3, W4, b1, b2, b3, b4, W5, flagp,
                                      P, Wp, biasf);

    const int MB128 = (N_NODES + 127) / 128;  // 157

    k_gemm_mfma<<<dim3(MB128, 4), 256, 0, stream>>>(P, (const unsigned short*)x, flagp,
                                                    Wp, H, N_NODES, 512, 512);
    k_agg_w<<<AGW, 64, 0, stream>>>(H, rowptr, csr_pair, selfnorm, biasf, P);
    k_gemm_mfma<<<dim3(MB128, 4), 256, 0, stream>>>(P, P, flagp,
                                                    Wp + (size_t)32768 * 8, H,
                                                    N_NODES, 512, 512);
    k_agg_w<<<AGW, 64, 0, stream>>>(H, rowptr, csr_pair, selfnorm, biasf + 512, P);
    k_gemm_mfma<<<dim3(MB128, 4), 256, 0, stream>>>(P, P, flagp,
                                                    Wp + (size_t)65536 * 8, H,
                                                    N_NODES, 512, 512);
    k_agg_w<<<AGW, 64, 0, stream>>>(H, rowptr, csr_pair, selfnorm, biasf + 1024, P);
    k_gemm_mfma<<<dim3(MB128, 2), 256, 0, stream>>>(P, P, flagp,
                                                    Wp + (size_t)98304 * 8, H,
                                                    N_NODES, 512, 256);
    k_agg_fuse<<<AGF, 64, 0, stream>>>(H, rowptr, csr_pair, selfnorm,
                                       biasf + 1536, biasf + 2048, h5);

    k_final<<<NB, 256, 0, stream>>>(h5, rowptr, csr_pair, selfnorm, b5, flagp,
                                    d_out);
}

// Round 10
// 436.037 us; speedup vs baseline: 1.1005x; 1.0939x over previous
//
#include <hip/hip_runtime.h>
#include <cstdint>
#include <cstddef>

#define N_NODES 20000
#define N_EDGES 400000
#define NBLK 79  // ceil(20000/256)
#define MPAD 20128  // N_NODES rounded up to 128-row tiles

typedef __attribute__((ext_vector_type(8))) short bf16x8;
typedef __attribute__((ext_vector_type(4))) float f32x4;
typedef __attribute__((ext_vector_type(2))) int i32x2;

// ---------- bf16 helpers (manual, bit-exact) ----------
__device__ __forceinline__ float bf2f(unsigned short u) {
    return __uint_as_float(((unsigned int)u) << 16);
}
__device__ __forceinline__ unsigned short f2bf(float f) {
    unsigned int x = __float_as_uint(f);
    unsigned int lsb = (x >> 16) & 1u;
    x += 0x7fffu + lsb;  // round-to-nearest-even
    return (unsigned short)(x >> 16);
}

// ---------- flag-aware loads for harness float tensors (bf16 or fp32) ----------
__device__ __forceinline__ float ldF(const void* p, size_t i, bool bf) {
    return bf ? bf2f(((const unsigned short*)p)[i]) : ((const float*)p)[i];
}

// ---------- async global->LDS 16B copy ----------
__device__ __forceinline__ void gl2lds16(const unsigned short* g, unsigned short* l) {
    __builtin_amdgcn_global_load_lds(
        (const __attribute__((address_space(1))) void*)g,
        (__attribute__((address_space(3))) void*)l, 16, 0, 0);
}

// ---------- dtype + int64 detection (one wave, lane-parallel) ----------
__global__ void k_detect(const unsigned int* __restrict__ xw, const int* __restrict__ raw,
                         int* __restrict__ flag) {
    int lane = threadIdx.x;
    int cnt = 0, nz = 0;
    for (int i = lane; i < 256; i += 64) {
        unsigned short lo = (unsigned short)(xw[i] & 0xffffu);
        int e = (lo >> 7) & 0xff;
        if (e >= 110 && e <= 135) cnt++;
    }
    for (int i = 2 * lane + 1; i < 512; i += 128)
        if (raw[i] != 0) nz++;
#pragma unroll
    for (int off = 32; off > 0; off >>= 1) {
        cnt += __shfl_down(cnt, off);
        nz  += __shfl_down(nz, off);
    }
    if (lane == 0) {
        flag[0] = (cnt >= 128) ? 1 : 0;  // 1 = float tensors are bf16
        flag[1] = (nz == 0) ? 1 : 0;     // 1 = edge_index is raw int64
    }
}

// ---------- degree + counts (reads raw edge_index directly) ----------
__global__ void k_canon_deg(const int* __restrict__ raw, const void* __restrict__ ew,
                            const int* __restrict__ flagp,
                            float* __restrict__ deg, int* __restrict__ counts) {
    bool bf = (flagp[0] != 0);
    int is64 = flagp[1];
    int e = blockIdx.x * blockDim.x + threadIdx.x;
    if (e >= N_EDGES) return;
    int d;
    if (is64) d = raw[2 * (N_EDGES + e)];
    else      d = raw[N_EDGES + e];
    atomicAdd(&deg[d], ldF(ew, e, bf));
    atomicAdd(&counts[d], 1);
}

// ---------- pass 1: per-block count sums + fused dinv/selfnorm ----------
__global__ __launch_bounds__(256) void k_part(const int* __restrict__ counts,
                                              const float* __restrict__ deg,
                                              float* __restrict__ dinv,
                                              float* __restrict__ selfnorm,
                                              int* __restrict__ bsum) {
    __shared__ int s[256];
    int t = threadIdx.x;
    int i = blockIdx.x * 256 + t;
    int c = (i < N_NODES) ? counts[i] : 0;
    if (i < N_NODES) {
        float d = deg[i] + 1.0f;
        float r = rsqrtf(d);
        dinv[i] = r;
        selfnorm[i] = r * r;
    }
    s[t] = c;
    __syncthreads();
    for (int off = 128; off > 0; off >>= 1) {
        if (t < off) s[t] += s[t + off];
        __syncthreads();
    }
    if (t == 0) bsum[blockIdx.x] = s[0];
}

// ---------- pass 2: exclusive scan of 79 block sums (1 tiny block) ----------
__global__ void k_scanb(const int* __restrict__ bsum, int* __restrict__ bofs,
                        int* __restrict__ rowptr) {
    __shared__ int s[128];
    int t = threadIdx.x;
    int v = (t < NBLK) ? bsum[t] : 0;
    s[t] = v;
    __syncthreads();
    for (int off = 1; off < 128; off <<= 1) {
        int u = (t >= off) ? s[t - off] : 0;
        __syncthreads();
        s[t] += u;
        __syncthreads();
    }
    if (t < NBLK) bofs[t] = s[t] - v;  // exclusive
    if (t == NBLK - 1) rowptr[N_NODES] = s[t];
}

// ---------- pass 3: intra-block scan + block offset -> rowptr ----------
__global__ __launch_bounds__(256) void k_row(const int* __restrict__ counts,
                                             const int* __restrict__ bofs,
                                             int* __restrict__ rowptr) {
    __shared__ int s[256];
    int t = threadIdx.x;
    int b = blockIdx.x;
    int i = b * 256 + t;
    int c = (i < N_NODES) ? counts[i] : 0;
    s[t] = c;
    __syncthreads();
    for (int off = 1; off < 256; off <<= 1) {
        int u = (t >= off) ? s[t - off] : 0;
        __syncthreads();
        s[t] += u;
        __syncthreads();
    }
    if (i < N_NODES) rowptr[i] = bofs[b] + s[t] - c;
}

// ---------- scatter edges into CSR-by-dst: packed (src, norm) pairs ----------
__global__ void k_csr(const int* __restrict__ raw, const void* __restrict__ ew,
                      const int* __restrict__ flagp,
                      const float* __restrict__ dinv, const int* __restrict__ rowptr,
                      int* __restrict__ fill, int* __restrict__ csr_pair) {
    bool bf = (flagp[0] != 0);
    int is64 = flagp[1];
    int e = blockIdx.x * blockDim.x + threadIdx.x;
    if (e >= N_EDGES) return;
    int s, d;
    if (is64) { s = raw[2 * e]; d = raw[2 * (N_EDGES + e)]; }
    else      { s = raw[e];     d = raw[N_EDGES + e]; }
    int p = rowptr[d] + atomicAdd(&fill[d], 1);
    float nrm = dinv[s] * ldF(ew, e, bf) * dinv[d];
    i32x2 pv;
    pv.x = s;
    pv.y = __float_as_int(nrm);
    *(i32x2*)(csr_pair + 2 * (size_t)p) = pv;
}

// ---------- prep: pack weights | cast biases + W5 -> fp32 (457 blocks) ----------
// x-cast removed: layer-1 GEMM reads x directly in either dtype (staging converts).
__global__ __launch_bounds__(256) void k_prep(const void* __restrict__ W1,
                                              const void* __restrict__ W2,
                                              const void* __restrict__ W3,
                                              const void* __restrict__ W4,
                                              const void* __restrict__ b1,
                                              const void* __restrict__ b2,
                                              const void* __restrict__ b3,
                                              const void* __restrict__ b4,
                                              const void* __restrict__ W5,
                                              const int* __restrict__ flagp,
                                              unsigned short* __restrict__ Wp,
                                              float* __restrict__ biasf) {
    bool bf = (*flagp != 0);
    int b = blockIdx.x;
    int t = threadIdx.x;
    if (b < 448) {
        int gidx = b * 256 + t;  // < 114688 exactly
        const void* W;
        int idx = gidx, N, nbl;
        if (gidx < 32768)      { W = W1; N = 512; nbl = 5; }
        else if (gidx < 65536) { W = W2; N = 512; nbl = 5; idx -= 32768; }
        else if (gidx < 98304) { W = W3; N = 512; nbl = 5; idx -= 65536; }
        else                   { W = W4; N = 256; nbl = 4; idx -= 98304; }
        int lane = idx & 63;
        int blk = idx >> 6;
        int nb = blk & ((1 << nbl) - 1);
        int kb = blk >> nbl;
        int n = (nb << 4) + (lane & 15);
        int kbase = (kb << 5) + ((lane >> 4) << 3);
        unsigned short o[8];
#pragma unroll
        for (int j = 0; j < 8; ++j)
            o[j] = f2bf(ldF(W, (size_t)(kbase + j) * N + n, bf));
        *(uint4*)(&Wp[(size_t)gidx * 8]) = *(const uint4*)o;
    } else {
        int i = (b - 448) * 256 + t;
        if (i >= 2304) return;
        if (i < 2048) {
            int L = i >> 9, r = i & 511;
            if (L == 3 && r >= 256) return;
            const void* bb = (L == 0) ? b1 : (L == 1) ? b2 : (L == 2) ? b3 : b4;
            biasf[i] = ldF(bb, r, bf);
        } else {
            biasf[i] = ldF(W5, i - 2048, bf);  // fp32 W5 at biasf[2048..2303]
        }
    }
}

// ---------- MFMA bf16 GEMM, 128x128 tile, BK=64: C = A * Wp(packed) ----------
// useX: layer-1 mode. A = x (harness tensor), staged as bf16 directly or
// converted from fp32 on the fly in staging. Rows clamped (x unpadded).
__global__ __launch_bounds__(256) void k_gemm_mfma(const unsigned short* __restrict__ Abase,
                                                   const void* __restrict__ Xraw,
                                                   const int* __restrict__ flagp,
                                                   int useX,
                                                   const unsigned short* __restrict__ Bp,
                                                   unsigned short* __restrict__ C,
                                                   int M, int K, int N) {
    const int AP = 72;  // A-tile row stride (64 + 8 pad) shorts -> 2-way-max banks
    __shared__ __align__(16) unsigned short As[128 * AP];  // 18432 B
    __shared__ __align__(16) unsigned short Bs[2 * 8 * 512];  // 16384 B
    bool bf = (*flagp != 0);
    bool cvt = useX && !bf;  // fp32 x -> convert in staging
    const unsigned short* A = useX ? (const unsigned short*)Xraw : Abase;
    const float* Af = (const float*)Xraw;
    int tid = threadIdx.x;
    int lane = tid & 63;
    int wave = tid >> 6;
    int wr = wave >> 1, wc = wave & 1;
    int row0 = blockIdx.x * 128;
    int col0 = blockIdx.y * 128;
    int nbt = N >> 4;
    int q = lane >> 4;
    int mm = lane & 15;

    f32x4 acc[4][4] = {};

    for (int kb2 = 0; kb2 < (K >> 6); ++kb2) {
        const unsigned short* breg0 = Bp + (((size_t)(2 * kb2) * nbt + (col0 >> 4)) << 9);
        const unsigned short* breg1 = Bp + (((size_t)(2 * kb2 + 1) * nbt + (col0 >> 4)) << 9);
        gl2lds16(breg0 + (size_t)tid * 8, &Bs[(size_t)tid * 8]);
        gl2lds16(breg0 + (size_t)(tid + 256) * 8, &Bs[(size_t)(tid + 256) * 8]);
        gl2lds16(breg1 + (size_t)tid * 8, &Bs[4096 + (size_t)tid * 8]);
        gl2lds16(breg1 + (size_t)(tid + 256) * 8, &Bs[4096 + (size_t)(tid + 256) * 8]);
#pragma unroll
        for (int i = 0; i < 4; ++i) {
            int c = tid + i * 256;
            int row = c >> 3, kq = c & 7;
            int grow = min(row0 + row, M - 1);  // clamp: x is unpadded
            size_t idx = (size_t)grow * K + (kb2 << 6) + (kq << 3);
            if (!cvt) {
                uint4 v = *(const uint4*)(&A[idx]);
                *(uint4*)(&As[row * AP + (kq << 3)]) = v;
            } else {
                float4 v0 = *(const float4*)(Af + idx);
                float4 v1 = *(const float4*)(Af + idx + 4);
                uint4 o;
                o.x = (unsigned int)f2bf(v0.x) | ((unsigned int)f2bf(v0.y) << 16);
                o.y = (unsigned int)f2bf(v0.z) | ((unsigned int)f2bf(v0.w) << 16);
                o.z = (unsigned int)f2bf(v1.x) | ((unsigned int)f2bf(v1.y) << 16);
                o.w = (unsigned int)f2bf(v1.z) | ((unsigned int)f2bf(v1.w) << 16);
                *(uint4*)(&As[row * AP + (kq << 3)]) = o;
            }
        }
        __syncthreads();
#pragma unroll
        for (int kk = 0; kk < 2; ++kk) {
            bf16x8 af[4], bfr[4];
#pragma unroll
            for (int mb = 0; mb < 4; ++mb)
                af[mb] = *(const bf16x8*)(&As[(wr * 64 + mb * 16 + mm) * AP + kk * 32 + q * 8]);
#pragma unroll
            for (int nb = 0; nb < 4; ++nb)
                bfr[nb] = *(const bf16x8*)(&Bs[kk * 4096 + ((wc * 4 + nb) * 64 + lane) * 8]);
#pragma unroll
            for (int mb = 0; mb < 4; ++mb)
#pragma unroll
                for (int nb = 0; nb < 4; ++nb)
                    acc[mb][nb] = __builtin_amdgcn_mfma_f32_16x16x32_bf16(
                        af[mb], bfr[nb], acc[mb][nb], 0, 0, 0);
        }
        __syncthreads();
    }
#pragma unroll
    for (int mb = 0; mb < 4; ++mb) {
#pragma unroll
        for (int r = 0; r < 4; ++r) {
            int grow = row0 + wr * 64 + mb * 16 + q * 4 + r;
            if (grow < M) {
#pragma unroll
                for (int nb = 0; nb < 4; ++nb) {
                    int gcol = col0 + wc * 64 + nb * 16 + mm;
                    C[(size_t)grow * N + gcol] = f2bf(acc[mb][nb][r]);
                }
            }
        }
    }
}

// ---------- 4-chunk XCD-pinned wave-per-node aggregate (F=512) ----------
// Byte-exact round-7 winner: 42.8 us, FETCH 90 MB, delivered ~10 TB/s (near the
// random-gather line-rate ceiling; R8/R9 showed deeper chunking loses to VALU).
__global__ __launch_bounds__(64) void k_agg_w(const unsigned short* __restrict__ h,
                                              const int* __restrict__ rowptr,
                                              const int* __restrict__ csr_pair,
                                              const float* __restrict__ selfnorm,
                                              const float* __restrict__ biasf,
                                              unsigned short* __restrict__ out) {
    constexpr int F = 512;
    int lane = threadIdx.x;
    int chunk = blockIdx.x & 3;
    int node = blockIdx.x >> 2;
    int e0 = rowptr[node], e1 = rowptr[node + 1];
    float sn = selfnorm[node];
    const unsigned short* hb = h + chunk * 128 + lane * 2;  // this lane's dword column

    float a0, a1;
    {
        unsigned int u = *(const unsigned int*)(hb + (size_t)node * F);
        a0 = sn * bf2f((unsigned short)(u & 0xffffu));
        a1 = sn * bf2f((unsigned short)(u >> 16));
    }
    const i32x2* pairs = (const i32x2*)csr_pair;
    int j = e0;
    for (; j + 7 < e1; j += 8) {
        i32x2 p0 = pairs[j],     p1 = pairs[j + 1], p2 = pairs[j + 2], p3 = pairs[j + 3];
        i32x2 p4 = pairs[j + 4], p5 = pairs[j + 5], p6 = pairs[j + 6], p7 = pairs[j + 7];
        unsigned int u0 = *(const unsigned int*)(hb + (size_t)p0.x * F);
        unsigned int u1 = *(const unsigned int*)(hb + (size_t)p1.x * F);
        unsigned int u2 = *(const unsigned int*)(hb + (size_t)p2.x * F);
        unsigned int u3 = *(const unsigned int*)(hb + (size_t)p3.x * F);
        unsigned int u4 = *(const unsigned int*)(hb + (size_t)p4.x * F);
        unsigned int u5 = *(const unsigned int*)(hb + (size_t)p5.x * F);
        unsigned int u6 = *(const unsigned int*)(hb + (size_t)p6.x * F);
        unsigned int u7 = *(const unsigned int*)(hb + (size_t)p7.x * F);
        float w0 = __int_as_float(p0.y), w1 = __int_as_float(p1.y);
        float w2 = __int_as_float(p2.y), w3 = __int_as_float(p3.y);
        float w4 = __int_as_float(p4.y), w5 = __int_as_float(p5.y);
        float w6 = __int_as_float(p6.y), w7 = __int_as_float(p7.y);
        a0 = fmaf(bf2f((unsigned short)(u0 & 0xffffu)), w0, a0);
        a1 = fmaf(bf2f((unsigned short)(u0 >> 16)),     w0, a1);
        a0 = fmaf(bf2f((unsigned short)(u1 & 0xffffu)), w1, a0);
        a1 = fmaf(bf2f((unsigned short)(u1 >> 16)),     w1, a1);
        a0 = fmaf(bf2f((unsigned short)(u2 & 0xffffu)), w2, a0);
        a1 = fmaf(bf2f((unsigned short)(u2 >> 16)),     w2, a1);
        a0 = fmaf(bf2f((unsigned short)(u3 & 0xffffu)), w3, a0);
        a1 = fmaf(bf2f((unsigned short)(u3 >> 16)),     w3, a1);
        a0 = fmaf(bf2f((unsigned short)(u4 & 0xffffu)), w4, a0);
        a1 = fmaf(bf2f((unsigned short)(u4 >> 16)),     w4, a1);
        a0 = fmaf(bf2f((unsigned short)(u5 & 0xffffu)), w5, a0);
        a1 = fmaf(bf2f((unsigned short)(u5 >> 16)),     w5, a1);
        a0 = fmaf(bf2f((unsigned short)(u6 & 0xffffu)), w6, a0);
        a1 = fmaf(bf2f((unsigned short)(u6 >> 16)),     w6, a1);
        a0 = fmaf(bf2f((unsigned short)(u7 & 0xffffu)), w7, a0);
        a1 = fmaf(bf2f((unsigned short)(u7 >> 16)),     w7, a1);
    }
    for (; j + 3 < e1; j += 4) {
        i32x2 p0 = pairs[j], p1 = pairs[j + 1], p2 = pairs[j + 2], p3 = pairs[j + 3];
        unsigned int u0 = *(const unsigned int*)(hb + (size_t)p0.x * F);
        unsigned int u1 = *(const unsigned int*)(hb + (size_t)p1.x * F);
        unsigned int u2 = *(const unsigned int*)(hb + (size_t)p2.x * F);
        unsigned int u3 = *(const unsigned int*)(hb + (size_t)p3.x * F);
        float w0 = __int_as_float(p0.y), w1 = __int_as_float(p1.y);
        float w2 = __int_as_float(p2.y), w3 = __int_as_float(p3.y);
        a0 = fmaf(bf2f((unsigned short)(u0 & 0xffffu)), w0, a0);
        a1 = fmaf(bf2f((unsigned short)(u0 >> 16)),     w0, a1);
        a0 = fmaf(bf2f((unsigned short)(u1 & 0xffffu)), w1, a0);
        a1 = fmaf(bf2f((unsigned short)(u1 >> 16)),     w1, a1);
        a0 = fmaf(bf2f((unsigned short)(u2 & 0xffffu)), w2, a0);
        a1 = fmaf(bf2f((unsigned short)(u2 >> 16)),     w2, a1);
        a0 = fmaf(bf2f((unsigned short)(u3 & 0xffffu)), w3, a0);
        a1 = fmaf(bf2f((unsigned short)(u3 >> 16)),     w3, a1);
    }
    for (; j < e1; ++j) {
        i32x2 p0 = pairs[j];
        unsigned int u0 = *(const unsigned int*)(hb + (size_t)p0.x * F);
        float w0 = __int_as_float(p0.y);
        a0 = fmaf(bf2f((unsigned short)(u0 & 0xffffu)), w0, a0);
        a1 = fmaf(bf2f((unsigned short)(u0 >> 16)),     w0, a1);
    }
    {
        const float* bp = biasf + chunk * 128 + lane * 2;
        a0 = fmaxf(a0 + bp[0], 0.f);
        a1 = fmaxf(a1 + bp[1], 0.f);
        unsigned int o = (unsigned int)f2bf(a0) | ((unsigned int)f2bf(a1) << 16);
        *(unsigned int*)(out + (size_t)node * F + chunk * 128 + lane * 2) = o;
    }
}

// ---------- L4 agg fused with L5 GEMV, 2-chunk XCD-pinned (F=256) ----------
// R7's chunk ratio applied to agg_fuse: 128-feat slice = 5.12 MB/XCD.
// Same instruction structure as k_agg_w; partial dot + atomicAdd into zeroed h5.
__global__ __launch_bounds__(64) void k_agg_fuse(const unsigned short* __restrict__ h,
                                                 const int* __restrict__ rowptr,
                                                 const int* __restrict__ csr_pair,
                                                 const float* __restrict__ selfnorm,
                                                 const float* __restrict__ biasf,
                                                 const float* __restrict__ w5f,
                                                 float* __restrict__ h5) {
    constexpr int F = 256;
    int lane = threadIdx.x;
    int chunk = blockIdx.x & 1;
    int node = blockIdx.x >> 1;
    int e0 = rowptr[node], e1 = rowptr[node + 1];
    float sn = selfnorm[node];
    const unsigned short* hb = h + chunk * 128 + lane * 2;

    float a0, a1;
    {
        unsigned int u = *(const unsigned int*)(hb + (size_t)node * F);
        a0 = sn * bf2f((unsigned short)(u & 0xffffu));
        a1 = sn * bf2f((unsigned short)(u >> 16));
    }
    const i32x2* pairs = (const i32x2*)csr_pair;
    int j = e0;
    for (; j + 7 < e1; j += 8) {
        i32x2 p0 = pairs[j],     p1 = pairs[j + 1], p2 = pairs[j + 2], p3 = pairs[j + 3];
        i32x2 p4 = pairs[j + 4], p5 = pairs[j + 5], p6 = pairs[j + 6], p7 = pairs[j + 7];
        unsigned int u0 = *(const unsigned int*)(hb + (size_t)p0.x * F);
        unsigned int u1 = *(const unsigned int*)(hb + (size_t)p1.x * F);
        unsigned int u2 = *(const unsigned int*)(hb + (size_t)p2.x * F);
        unsigned int u3 = *(const unsigned int*)(hb + (size_t)p3.x * F);
        unsigned int u4 = *(const unsigned int*)(hb + (size_t)p4.x * F);
        unsigned int u5 = *(const unsigned int*)(hb + (size_t)p5.x * F);
        unsigned int u6 = *(const unsigned int*)(hb + (size_t)p6.x * F);
        unsigned int u7 = *(const unsigned int*)(hb + (size_t)p7.x * F);
        float w0 = __int_as_float(p0.y), w1 = __int_as_float(p1.y);
        float w2 = __int_as_float(p2.y), w3 = __int_as_float(p3.y);
        float w4 = __int_as_float(p4.y), w5 = __int_as_float(p5.y);
        float w6 = __int_as_float(p6.y), w7 = __int_as_float(p7.y);
        a0 = fmaf(bf2f((unsigned short)(u0 & 0xffffu)), w0, a0);
        a1 = fmaf(bf2f((unsigned short)(u0 >> 16)),     w0, a1);
        a0 = fmaf(bf2f((unsigned short)(u1 & 0xffffu)), w1, a0);
        a1 = fmaf(bf2f((unsigned short)(u1 >> 16)),     w1, a1);
        a0 = fmaf(bf2f((unsigned short)(u2 & 0xffffu)), w2, a0);
        a1 = fmaf(bf2f((unsigned short)(u2 >> 16)),     w2, a1);
        a0 = fmaf(bf2f((unsigned short)(u3 & 0xffffu)), w3, a0);
        a1 = fmaf(bf2f((unsigned short)(u3 >> 16)),     w3, a1);
        a0 = fmaf(bf2f((unsigned short)(u4 & 0xffffu)), w4, a0);
        a1 = fmaf(bf2f((unsigned short)(u4 >> 16)),     w4, a1);
        a0 = fmaf(bf2f((unsigned short)(u5 & 0xffffu)), w5, a0);
        a1 = fmaf(bf2f((unsigned short)(u5 >> 16)),     w5, a1);
        a0 = fmaf(bf2f((unsigned short)(u6 & 0xffffu)), w6, a0);
        a1 = fmaf(bf2f((unsigned short)(u6 >> 16)),     w6, a1);
        a0 = fmaf(bf2f((unsigned short)(u7 & 0xffffu)), w7, a0);
        a1 = fmaf(bf2f((unsigned short)(u7 >> 16)),     w7, a1);
    }
    for (; j < e1; ++j) {
        i32x2 p0 = pairs[j];
        unsigned int u0 = *(const unsigned int*)(hb + (size_t)p0.x * F);
        float w0 = __int_as_float(p0.y);
        a0 = fmaf(bf2f((unsigned short)(u0 & 0xffffu)), w0, a0);
        a1 = fmaf(bf2f((unsigned short)(u0 >> 16)),     w0, a1);
    }
    {
        const float* bp = biasf + chunk * 128 + lane * 2;
        const float* wp = w5f + chunk * 128 + lane * 2;
        float partial = fmaxf(a0 + bp[0], 0.f) * wp[0]
                      + fmaxf(a1 + bp[1], 0.f) * wp[1];
#pragma unroll
        for (int off = 32; off > 0; off >>= 1)
            partial += __shfl_xor(partial, off);
        if (lane == 0) atomicAdd(h5 + node, partial);
    }
}

// ---------- final scalar aggregate, write output in harness dtype ----------
__global__ void k_final(const float* __restrict__ h5, const int* __restrict__ rowptr,
                        const int* __restrict__ csr_pair,
                        const float* __restrict__ selfnorm,
                        const void* __restrict__ b5, const int* __restrict__ flagp,
                        void* __restrict__ out) {
    bool bf = (*flagp != 0);
    int i = blockIdx.x * blockDim.x + threadIdx.x;
    if (i >= N_NODES) return;
    float acc = selfnorm[i] * h5[i];
    int e0 = rowptr[i], e1 = rowptr[i + 1];
    for (int j = e0; j < e1; ++j) {
        int s = csr_pair[2 * (size_t)j];
        float w = __int_as_float(csr_pair[2 * (size_t)j + 1]);
        acc += w * h5[s];
    }
    acc += ldF(b5, 0, bf);
    if (bf) ((unsigned short*)out)[i] = f2bf(acc);
    else    ((float*)out)[i] = acc;
}

extern "C" void kernel_launch(void* const* d_in, const int* in_sizes, int n_in,
                              void* d_out, int out_size, void* d_ws, size_t ws_size,
                              hipStream_t stream) {
    const void* x  = d_in[0];
    const int*  ei = (const int*)d_in[1];
    const void* ea = d_in[2];
    const void* W1 = d_in[3];
    const void* b1 = d_in[4];
    const void* W2 = d_in[5];
    const void* b2 = d_in[6];
    const void* W3 = d_in[7];
    const void* b3 = d_in[8];
    const void* W4 = d_in[9];
    const void* b4 = d_in[10];
    const void* W5 = d_in[11];
    const void* b5 = d_in[12];

    char* ws = (char*)d_ws;
    size_t off = 0;
    auto take = [&](size_t bytes) -> void* {
        off = (off + 255) & ~(size_t)255;
        void* p = ws + off;
        off += bytes;
        return p;
    };
    int*   flagp    = (int*)take(2 * sizeof(int));
    float* deg      = (float*)take(N_NODES * sizeof(float));
    int*   counts   = (int*)take(N_NODES * sizeof(int));
    int*   fill     = (int*)take(N_NODES * sizeof(int));
    float* h5       = (float*)take(N_NODES * sizeof(float));  // zeroed: atomic acc
    size_t zspan    = (size_t)((char*)(h5 + N_NODES) - (char*)deg);
    float* dinv     = (float*)take(N_NODES * sizeof(float));
    float* selfnorm = (float*)take(N_NODES * sizeof(float));
    float* biasf    = (float*)take(2304 * sizeof(float));  // 4x512 biases + 256 W5
    int*   bsum     = (int*)take(128 * sizeof(int));
    int*   bofs     = (int*)take(128 * sizeof(int));
    int*   rowptr   = (int*)take((N_NODES + 1) * sizeof(int));
    int*   csr_pair = (int*)take((size_t)N_EDGES * 2 * sizeof(int));  // (src, normbits)
    unsigned short* Wp = (unsigned short*)take((size_t)114688 * 8 * sizeof(unsigned short));
    unsigned short* P  = (unsigned short*)take((size_t)MPAD * 512 * sizeof(unsigned short));
    unsigned short* H  = (unsigned short*)take((size_t)MPAD * 512 * sizeof(unsigned short));

    (void)hipMemsetAsync(deg, 0, zspan, stream);

    const int EB = (N_EDGES + 255) / 256;
    const int NB = (N_NODES + 255) / 256;  // 79 == NBLK
    const int AGW = N_NODES * 4;  // 4 chunks per node (R7 winner)
    const int AGF = N_NODES * 2;  // 2 chunks per node

    k_detect<<<1, 64, 0, stream>>>((const unsigned int*)x, ei, flagp);
    k_canon_deg<<<EB, 256, 0, stream>>>(ei, ea, flagp, deg, counts);
    k_part<<<NB, 256, 0, stream>>>(counts, deg, dinv, selfnorm, bsum);
    k_scanb<<<1, 128, 0, stream>>>(bsum, bofs, rowptr);
    k_row<<<NB, 256, 0, stream>>>(counts, bofs, rowptr);
    k_csr<<<EB, 256, 0, stream>>>(ei, ea, flagp, dinv, rowptr, fill, csr_pair);

    k_prep<<<457, 256, 0, stream>>>(W1, W2, W3, W4, b1, b2, b3, b4, W5, flagp,
                                    Wp, biasf);

    const int MB128 = (N_NODES + 127) / 128;  // 157

    k_gemm_mfma<<<dim3(MB128, 4), 256, 0, stream>>>(P, x, flagp, 1,
                                                    Wp, H, N_NODES, 512, 512);
    k_agg_w<<<AGW, 64, 0, stream>>>(H, rowptr, csr_pair, selfnorm, biasf, P);
    k_gemm_mfma<<<dim3(MB128, 4), 256, 0, stream>>>(P, x, flagp, 0,
                                                    Wp + (size_t)32768 * 8, H,
                                                    N_NODES, 512, 512);
    k_agg_w<<<AGW, 64, 0, stream>>>(H, rowptr, csr_pair, selfnorm, biasf + 512, P);
    k_gemm_mfma<<<dim3(MB128, 4), 256, 0, stream>>>(P, x, flagp, 0,
                                                    Wp + (size_t)65536 * 8, H,
                                                    N_NODES, 512, 512);
    k_agg_w<<<AGW, 64, 0, stream>>>(H, rowptr, csr_pair, selfnorm, biasf + 1024, P);
    k_gemm_mfma<<<dim3(MB128, 2), 256, 0, stream>>>(P, x, flagp, 0,
                                                    Wp + (size_t)98304 * 8, H,
                                                    N_NODES, 512, 256);
    k_agg_fuse<<<AGF, 64, 0, stream>>>(H, rowptr, csr_pair, selfnorm,
                                       biasf + 1536, biasf + 2048, h5);

    k_final<<<NB, 256, 0, stream>>>(h5, rowptr, csr_pair, selfnorm, b5, flagp,
                                    d_out);
}

// Round 11
// 434.034 us; speedup vs baseline: 1.1056x; 1.0046x over previous
//
#include <hip/hip_runtime.h>
#include <cstdint>
#include <cstddef>

#define N_NODES 20000
#define N_EDGES 400000
#define NBLK 79  // ceil(20000/256)
#define MPAD 20128  // N_NODES rounded up to 128-row tiles

typedef __attribute__((ext_vector_type(8))) short bf16x8;
typedef __attribute__((ext_vector_type(4))) float f32x4;
typedef __attribute__((ext_vector_type(2))) int i32x2;

// ---------- bf16 helpers (manual, bit-exact) ----------
__device__ __forceinline__ float bf2f(unsigned short u) {
    return __uint_as_float(((unsigned int)u) << 16);
}
__device__ __forceinline__ unsigned short f2bf(float f) {
    unsigned int x = __float_as_uint(f);
    unsigned int lsb = (x >> 16) & 1u;
    x += 0x7fffu + lsb;  // round-to-nearest-even
    return (unsigned short)(x >> 16);
}

// ---------- flag-aware loads for harness float tensors (bf16 or fp32) ----------
__device__ __forceinline__ float ldF(const void* p, size_t i, bool bf) {
    return bf ? bf2f(((const unsigned short*)p)[i]) : ((const float*)p)[i];
}

// ---------- async global->LDS 16B copy ----------
__device__ __forceinline__ void gl2lds16(const unsigned short* g, unsigned short* l) {
    __builtin_amdgcn_global_load_lds(
        (const __attribute__((address_space(1))) void*)g,
        (__attribute__((address_space(3))) void*)l, 16, 0, 0);
}

// ---------- dtype + int64 detection (one wave, lane-parallel) ----------
__global__ void k_detect(const unsigned int* __restrict__ xw, const int* __restrict__ raw,
                         int* __restrict__ flag) {
    int lane = threadIdx.x;
    int cnt = 0, nz = 0;
    for (int i = lane; i < 256; i += 64) {
        unsigned short lo = (unsigned short)(xw[i] & 0xffffu);
        int e = (lo >> 7) & 0xff;
        if (e >= 110 && e <= 135) cnt++;
    }
    for (int i = 2 * lane + 1; i < 512; i += 128)
        if (raw[i] != 0) nz++;
#pragma unroll
    for (int off = 32; off > 0; off >>= 1) {
        cnt += __shfl_down(cnt, off);
        nz  += __shfl_down(nz, off);
    }
    if (lane == 0) {
        flag[0] = (cnt >= 128) ? 1 : 0;  // 1 = float tensors are bf16
        flag[1] = (nz == 0) ? 1 : 0;     // 1 = edge_index is raw int64
    }
}

// ---------- degree + counts (reads raw edge_index directly) ----------
__global__ void k_canon_deg(const int* __restrict__ raw, const void* __restrict__ ew,
                            const int* __restrict__ flagp,
                            float* __restrict__ deg, int* __restrict__ counts) {
    bool bf = (flagp[0] != 0);
    int is64 = flagp[1];
    int e = blockIdx.x * blockDim.x + threadIdx.x;
    if (e >= N_EDGES) return;
    int d;
    if (is64) d = raw[2 * (N_EDGES + e)];
    else      d = raw[N_EDGES + e];
    atomicAdd(&deg[d], ldF(ew, e, bf));
    atomicAdd(&counts[d], 1);
}

// ---------- pass 1: per-block count sums + fused dinv/selfnorm ----------
__global__ __launch_bounds__(256) void k_part(const int* __restrict__ counts,
                                              const float* __restrict__ deg,
                                              float* __restrict__ dinv,
                                              float* __restrict__ selfnorm,
                                              int* __restrict__ bsum) {
    __shared__ int s[256];
    int t = threadIdx.x;
    int i = blockIdx.x * 256 + t;
    int c = (i < N_NODES) ? counts[i] : 0;
    if (i < N_NODES) {
        float d = deg[i] + 1.0f;
        float r = rsqrtf(d);
        dinv[i] = r;
        selfnorm[i] = r * r;
    }
    s[t] = c;
    __syncthreads();
    for (int off = 128; off > 0; off >>= 1) {
        if (t < off) s[t] += s[t + off];
        __syncthreads();
    }
    if (t == 0) bsum[blockIdx.x] = s[0];
}

// ---------- pass 2: exclusive scan of 79 block sums (1 tiny block) ----------
__global__ void k_scanb(const int* __restrict__ bsum, int* __restrict__ bofs,
                        int* __restrict__ rowptr) {
    __shared__ int s[128];
    int t = threadIdx.x;
    int v = (t < NBLK) ? bsum[t] : 0;
    s[t] = v;
    __syncthreads();
    for (int off = 1; off < 128; off <<= 1) {
        int u = (t >= off) ? s[t - off] : 0;
        __syncthreads();
        s[t] += u;
        __syncthreads();
    }
    if (t < NBLK) bofs[t] = s[t] - v;  // exclusive
    if (t == NBLK - 1) rowptr[N_NODES] = s[t];
}

// ---------- pass 3: intra-block scan + block offset -> rowptr ----------
__global__ __launch_bounds__(256) void k_row(const int* __restrict__ counts,
                                             const int* __restrict__ bofs,
                                             int* __restrict__ rowptr) {
    __shared__ int s[256];
    int t = threadIdx.x;
    int b = blockIdx.x;
    int i = b * 256 + t;
    int c = (i < N_NODES) ? counts[i] : 0;
    s[t] = c;
    __syncthreads();
    for (int off = 1; off < 256; off <<= 1) {
        int u = (t >= off) ? s[t - off] : 0;
        __syncthreads();
        s[t] += u;
        __syncthreads();
    }
    if (i < N_NODES) rowptr[i] = bofs[b] + s[t] - c;
}

// ---------- scatter edges into CSR-by-dst: packed (src, norm) pairs ----------
__global__ void k_csr(const int* __restrict__ raw, const void* __restrict__ ew,
                      const int* __restrict__ flagp,
                      const float* __restrict__ dinv, const int* __restrict__ rowptr,
                      int* __restrict__ fill, int* __restrict__ csr_pair) {
    bool bf = (flagp[0] != 0);
    int is64 = flagp[1];
    int e = blockIdx.x * blockDim.x + threadIdx.x;
    if (e >= N_EDGES) return;
    int s, d;
    if (is64) { s = raw[2 * e]; d = raw[2 * (N_EDGES + e)]; }
    else      { s = raw[e];     d = raw[N_EDGES + e]; }
    int p = rowptr[d] + atomicAdd(&fill[d], 1);
    float nrm = dinv[s] * ldF(ew, e, bf) * dinv[d];
    i32x2 pv;
    pv.x = s;
    pv.y = __float_as_int(nrm);
    *(i32x2*)(csr_pair + 2 * (size_t)p) = pv;
}

// ---------- prep: pack weights | cast biases + W5 -> fp32 (457 blocks) ----------
// x-cast removed: layer-1 GEMM reads x directly in either dtype (staging converts).
__global__ __launch_bounds__(256) void k_prep(const void* __restrict__ W1,
                                              const void* __restrict__ W2,
                                              const void* __restrict__ W3,
                                              const void* __restrict__ W4,
                                              const void* __restrict__ b1,
                                              const void* __restrict__ b2,
                                              const void* __restrict__ b3,
                                              const void* __restrict__ b4,
                                              const void* __restrict__ W5,
                                              const int* __restrict__ flagp,
                                              unsigned short* __restrict__ Wp,
                                              float* __restrict__ biasf) {
    bool bf = (*flagp != 0);
    int b = blockIdx.x;
    int t = threadIdx.x;
    if (b < 448) {
        int gidx = b * 256 + t;  // < 114688 exactly
        const void* W;
        int idx = gidx, N, nbl;
        if (gidx < 32768)      { W = W1; N = 512; nbl = 5; }
        else if (gidx < 65536) { W = W2; N = 512; nbl = 5; idx -= 32768; }
        else if (gidx < 98304) { W = W3; N = 512; nbl = 5; idx -= 65536; }
        else                   { W = W4; N = 256; nbl = 4; idx -= 98304; }
        int lane = idx & 63;
        int blk = idx >> 6;
        int nb = blk & ((1 << nbl) - 1);
        int kb = blk >> nbl;
        int n = (nb << 4) + (lane & 15);
        int kbase = (kb << 5) + ((lane >> 4) << 3);
        unsigned short o[8];
#pragma unroll
        for (int j = 0; j < 8; ++j)
            o[j] = f2bf(ldF(W, (size_t)(kbase + j) * N + n, bf));
        *(uint4*)(&Wp[(size_t)gidx * 8]) = *(const uint4*)o;
    } else {
        int i = (b - 448) * 256 + t;
        if (i >= 2304) return;
        if (i < 2048) {
            int L = i >> 9, r = i & 511;
            if (L == 3 && r >= 256) return;
            const void* bb = (L == 0) ? b1 : (L == 1) ? b2 : (L == 2) ? b3 : b4;
            biasf[i] = ldF(bb, r, bf);
        } else {
            biasf[i] = ldF(W5, i - 2048, bf);  // fp32 W5 at biasf[2048..2303]
        }
    }
}

// ---------- MFMA bf16 GEMM, 128x128 tile, BK=64: C = A * Wp(packed) ----------
// useX: layer-1 mode. A = x (harness tensor), staged as bf16 directly or
// converted from fp32 on the fly in staging. Rows clamped (x unpadded).
__global__ __launch_bounds__(256) void k_gemm_mfma(const unsigned short* __restrict__ Abase,
                                                   const void* __restrict__ Xraw,
                                                   const int* __restrict__ flagp,
                                                   int useX,
                                                   const unsigned short* __restrict__ Bp,
                                                   unsigned short* __restrict__ C,
                                                   int M, int K, int N) {
    const int AP = 72;  // A-tile row stride (64 + 8 pad) shorts -> 2-way-max banks
    __shared__ __align__(16) unsigned short As[128 * AP];  // 18432 B
    __shared__ __align__(16) unsigned short Bs[2 * 8 * 512];  // 16384 B
    bool bf = (*flagp != 0);
    bool cvt = useX && !bf;  // fp32 x -> convert in staging
    const unsigned short* A = useX ? (const unsigned short*)Xraw : Abase;
    const float* Af = (const float*)Xraw;
    int tid = threadIdx.x;
    int lane = tid & 63;
    int wave = tid >> 6;
    int wr = wave >> 1, wc = wave & 1;
    int row0 = blockIdx.x * 128;
    int col0 = blockIdx.y * 128;
    int nbt = N >> 4;
    int q = lane >> 4;
    int mm = lane & 15;

    f32x4 acc[4][4] = {};

    for (int kb2 = 0; kb2 < (K >> 6); ++kb2) {
        const unsigned short* breg0 = Bp + (((size_t)(2 * kb2) * nbt + (col0 >> 4)) << 9);
        const unsigned short* breg1 = Bp + (((size_t)(2 * kb2 + 1) * nbt + (col0 >> 4)) << 9);
        gl2lds16(breg0 + (size_t)tid * 8, &Bs[(size_t)tid * 8]);
        gl2lds16(breg0 + (size_t)(tid + 256) * 8, &Bs[(size_t)(tid + 256) * 8]);
        gl2lds16(breg1 + (size_t)tid * 8, &Bs[4096 + (size_t)tid * 8]);
        gl2lds16(breg1 + (size_t)(tid + 256) * 8, &Bs[4096 + (size_t)(tid + 256) * 8]);
#pragma unroll
        for (int i = 0; i < 4; ++i) {
            int c = tid + i * 256;
            int row = c >> 3, kq = c & 7;
            int grow = min(row0 + row, M - 1);  // clamp: x is unpadded
            size_t idx = (size_t)grow * K + (kb2 << 6) + (kq << 3);
            if (!cvt) {
                uint4 v = *(const uint4*)(&A[idx]);
                *(uint4*)(&As[row * AP + (kq << 3)]) = v;
            } else {
                float4 v0 = *(const float4*)(Af + idx);
                float4 v1 = *(const float4*)(Af + idx + 4);
                uint4 o;
                o.x = (unsigned int)f2bf(v0.x) | ((unsigned int)f2bf(v0.y) << 16);
                o.y = (unsigned int)f2bf(v0.z) | ((unsigned int)f2bf(v0.w) << 16);
                o.z = (unsigned int)f2bf(v1.x) | ((unsigned int)f2bf(v1.y) << 16);
                o.w = (unsigned int)f2bf(v1.z) | ((unsigned int)f2bf(v1.w) << 16);
                *(uint4*)(&As[row * AP + (kq << 3)]) = o;
            }
        }
        __syncthreads();
#pragma unroll
        for (int kk = 0; kk < 2; ++kk) {
            bf16x8 af[4], bfr[4];
#pragma unroll
            for (int mb = 0; mb < 4; ++mb)
                af[mb] = *(const bf16x8*)(&As[(wr * 64 + mb * 16 + mm) * AP + kk * 32 + q * 8]);
#pragma unroll
            for (int nb = 0; nb < 4; ++nb)
                bfr[nb] = *(const bf16x8*)(&Bs[kk * 4096 + ((wc * 4 + nb) * 64 + lane) * 8]);
#pragma unroll
            for (int mb = 0; mb < 4; ++mb)
#pragma unroll
                for (int nb = 0; nb < 4; ++nb)
                    acc[mb][nb] = __builtin_amdgcn_mfma_f32_16x16x32_bf16(
                        af[mb], bfr[nb], acc[mb][nb], 0, 0, 0);
        }
        __syncthreads();
    }
#pragma unroll
    for (int mb = 0; mb < 4; ++mb) {
#pragma unroll
        for (int r = 0; r < 4; ++r) {
            int grow = row0 + wr * 64 + mb * 16 + q * 4 + r;
            if (grow < M) {
#pragma unroll
                for (int nb = 0; nb < 4; ++nb) {
                    int gcol = col0 + wc * 64 + nb * 16 + mm;
                    C[(size_t)grow * N + gcol] = f2bf(acc[mb][nb][r]);
                }
            }
        }
    }
}

// ---------- row-load + fma helpers for the gather ----------
template <int W>
__device__ __forceinline__ void ldrow(const unsigned short* h, size_t row, int F, int lane,
                                      unsigned int* u) {
    const unsigned int* p = (const unsigned int*)(h + row * F) + lane * W;
    if constexpr (W == 4) {
        uint4 v = *(const uint4*)p; u[0] = v.x; u[1] = v.y; u[2] = v.z; u[3] = v.w;
    } else {
        uint2 v = *(const uint2*)p; u[0] = v.x; u[1] = v.y;
    }
}
template <int W>
__device__ __forceinline__ void fmarow(const unsigned int* u, float w, float* acc) {
#pragma unroll
    for (int k = 0; k < W; ++k) {
        acc[2 * k]     = fmaf(bf2f((unsigned short)(u[k] & 0xffffu)), w, acc[2 * k]);
        acc[2 * k + 1] = fmaf(bf2f((unsigned short)(u[k] >> 16)),     w, acc[2 * k + 1]);
    }
}

// ---------- 4-chunk XCD-pinned wave-per-node aggregate (F=512) ----------
// Byte-exact round-7 winner: 42.8 us, FETCH 90 MB, delivered ~10 TB/s (near the
// random-gather line-rate ceiling; R8/R9 showed deeper chunking loses to VALU).
__global__ __launch_bounds__(64) void k_agg_w(const unsigned short* __restrict__ h,
                                              const int* __restrict__ rowptr,
                                              const int* __restrict__ csr_pair,
                                              const float* __restrict__ selfnorm,
                                              const float* __restrict__ biasf,
                                              unsigned short* __restrict__ out) {
    constexpr int F = 512;
    int lane = threadIdx.x;
    int chunk = blockIdx.x & 3;
    int node = blockIdx.x >> 2;
    int e0 = rowptr[node], e1 = rowptr[node + 1];
    float sn = selfnorm[node];
    const unsigned short* hb = h + chunk * 128 + lane * 2;  // this lane's dword column

    float a0, a1;
    {
        unsigned int u = *(const unsigned int*)(hb + (size_t)node * F);
        a0 = sn * bf2f((unsigned short)(u & 0xffffu));
        a1 = sn * bf2f((unsigned short)(u >> 16));
    }
    const i32x2* pairs = (const i32x2*)csr_pair;
    int j = e0;
    for (; j + 7 < e1; j += 8) {
        i32x2 p0 = pairs[j],     p1 = pairs[j + 1], p2 = pairs[j + 2], p3 = pairs[j + 3];
        i32x2 p4 = pairs[j + 4], p5 = pairs[j + 5], p6 = pairs[j + 6], p7 = pairs[j + 7];
        unsigned int u0 = *(const unsigned int*)(hb + (size_t)p0.x * F);
        unsigned int u1 = *(const unsigned int*)(hb + (size_t)p1.x * F);
        unsigned int u2 = *(const unsigned int*)(hb + (size_t)p2.x * F);
        unsigned int u3 = *(const unsigned int*)(hb + (size_t)p3.x * F);
        unsigned int u4 = *(const unsigned int*)(hb + (size_t)p4.x * F);
        unsigned int u5 = *(const unsigned int*)(hb + (size_t)p5.x * F);
        unsigned int u6 = *(const unsigned int*)(hb + (size_t)p6.x * F);
        unsigned int u7 = *(const unsigned int*)(hb + (size_t)p7.x * F);
        float w0 = __int_as_float(p0.y), w1 = __int_as_float(p1.y);
        float w2 = __int_as_float(p2.y), w3 = __int_as_float(p3.y);
        float w4 = __int_as_float(p4.y), w5 = __int_as_float(p5.y);
        float w6 = __int_as_float(p6.y), w7 = __int_as_float(p7.y);
        a0 = fmaf(bf2f((unsigned short)(u0 & 0xffffu)), w0, a0);
        a1 = fmaf(bf2f((unsigned short)(u0 >> 16)),     w0, a1);
        a0 = fmaf(bf2f((unsigned short)(u1 & 0xffffu)), w1, a0);
        a1 = fmaf(bf2f((unsigned short)(u1 >> 16)),     w1, a1);
        a0 = fmaf(bf2f((unsigned short)(u2 & 0xffffu)), w2, a0);
        a1 = fmaf(bf2f((unsigned short)(u2 >> 16)),     w2, a1);
        a0 = fmaf(bf2f((unsigned short)(u3 & 0xffffu)), w3, a0);
        a1 = fmaf(bf2f((unsigned short)(u3 >> 16)),     w3, a1);
        a0 = fmaf(bf2f((unsigned short)(u4 & 0xffffu)), w4, a0);
        a1 = fmaf(bf2f((unsigned short)(u4 >> 16)),     w4, a1);
        a0 = fmaf(bf2f((unsigned short)(u5 & 0xffffu)), w5, a0);
        a1 = fmaf(bf2f((unsigned short)(u5 >> 16)),     w5, a1);
        a0 = fmaf(bf2f((unsigned short)(u6 & 0xffffu)), w6, a0);
        a1 = fmaf(bf2f((unsigned short)(u6 >> 16)),     w6, a1);
        a0 = fmaf(bf2f((unsigned short)(u7 & 0xffffu)), w7, a0);
        a1 = fmaf(bf2f((unsigned short)(u7 >> 16)),     w7, a1);
    }
    for (; j + 3 < e1; j += 4) {
        i32x2 p0 = pairs[j], p1 = pairs[j + 1], p2 = pairs[j + 2], p3 = pairs[j + 3];
        unsigned int u0 = *(const unsigned int*)(hb + (size_t)p0.x * F);
        unsigned int u1 = *(const unsigned int*)(hb + (size_t)p1.x * F);
        unsigned int u2 = *(const unsigned int*)(hb + (size_t)p2.x * F);
        unsigned int u3 = *(const unsigned int*)(hb + (size_t)p3.x * F);
        float w0 = __int_as_float(p0.y), w1 = __int_as_float(p1.y);
        float w2 = __int_as_float(p2.y), w3 = __int_as_float(p3.y);
        a0 = fmaf(bf2f((unsigned short)(u0 & 0xffffu)), w0, a0);
        a1 = fmaf(bf2f((unsigned short)(u0 >> 16)),     w0, a1);
        a0 = fmaf(bf2f((unsigned short)(u1 & 0xffffu)), w1, a0);
        a1 = fmaf(bf2f((unsigned short)(u1 >> 16)),     w1, a1);
        a0 = fmaf(bf2f((unsigned short)(u2 & 0xffffu)), w2, a0);
        a1 = fmaf(bf2f((unsigned short)(u2 >> 16)),     w2, a1);
        a0 = fmaf(bf2f((unsigned short)(u3 & 0xffffu)), w3, a0);
        a1 = fmaf(bf2f((unsigned short)(u3 >> 16)),     w3, a1);
    }
    for (; j < e1; ++j) {
        i32x2 p0 = pairs[j];
        unsigned int u0 = *(const unsigned int*)(hb + (size_t)p0.x * F);
        float w0 = __int_as_float(p0.y);
        a0 = fmaf(bf2f((unsigned short)(u0 & 0xffffu)), w0, a0);
        a1 = fmaf(bf2f((unsigned short)(u0 >> 16)),     w0, a1);
    }
    {
        const float* bp = biasf + chunk * 128 + lane * 2;
        a0 = fmaxf(a0 + bp[0], 0.f);
        a1 = fmaxf(a1 + bp[1], 0.f);
        unsigned int o = (unsigned int)f2bf(a0) | ((unsigned int)f2bf(a1) << 16);
        *(unsigned int*)(out + (size_t)node * F + chunk * 128 + lane * 2) = o;
    }
}

// ---------- L4 agg fused with L5 GEMV: whole-row (F=256), 1-wave blocks ----------
// Reverted to the R6/R7 proven form: row is only 512 B so chunking just doubles
// CSR/loop overhead (R10 regression). Direct h5 store, no atomic.
__global__ __launch_bounds__(64) void k_agg_fuse(const unsigned short* __restrict__ h,
                                                 const int* __restrict__ rowptr,
                                                 const int* __restrict__ csr_pair,
                                                 const float* __restrict__ selfnorm,
                                                 const float* __restrict__ biasf,
                                                 const float* __restrict__ w5f,
                                                 float* __restrict__ h5) {
    constexpr int F = 256, FPL = 4, W = 2;
    int lane = threadIdx.x;
    int node = blockIdx.x;
    int e0 = rowptr[node], e1 = rowptr[node + 1];
    float sn = selfnorm[node];

    float acc[FPL];
    {
        unsigned int u[W];
        ldrow<W>(h, (size_t)node, F, lane, u);
#pragma unroll
        for (int k = 0; k < W; ++k) {
            acc[2 * k]     = sn * bf2f((unsigned short)(u[k] & 0xffffu));
            acc[2 * k + 1] = sn * bf2f((unsigned short)(u[k] >> 16));
        }
    }
    const i32x2* pairs = (const i32x2*)csr_pair;
    int j = e0;
    for (; j + 7 < e1; j += 8) {
        i32x2 p0 = pairs[j],     p1 = pairs[j + 1], p2 = pairs[j + 2], p3 = pairs[j + 3];
        i32x2 p4 = pairs[j + 4], p5 = pairs[j + 5], p6 = pairs[j + 6], p7 = pairs[j + 7];
        unsigned int u0[W], u1[W], u2[W], u3[W], u4[W], u5[W], u6[W], u7[W];
        ldrow<W>(h, (size_t)p0.x, F, lane, u0);
        ldrow<W>(h, (size_t)p1.x, F, lane, u1);
        ldrow<W>(h, (size_t)p2.x, F, lane, u2);
        ldrow<W>(h, (size_t)p3.x, F, lane, u3);
        ldrow<W>(h, (size_t)p4.x, F, lane, u4);
        ldrow<W>(h, (size_t)p5.x, F, lane, u5);
        ldrow<W>(h, (size_t)p6.x, F, lane, u6);
        ldrow<W>(h, (size_t)p7.x, F, lane, u7);
        fmarow<W>(u0, __int_as_float(p0.y), acc);
        fmarow<W>(u1, __int_as_float(p1.y), acc);
        fmarow<W>(u2, __int_as_float(p2.y), acc);
        fmarow<W>(u3, __int_as_float(p3.y), acc);
        fmarow<W>(u4, __int_as_float(p4.y), acc);
        fmarow<W>(u5, __int_as_float(p5.y), acc);
        fmarow<W>(u6, __int_as_float(p6.y), acc);
        fmarow<W>(u7, __int_as_float(p7.y), acc);
    }
    for (; j + 3 < e1; j += 4) {
        i32x2 p0 = pairs[j], p1 = pairs[j + 1], p2 = pairs[j + 2], p3 = pairs[j + 3];
        unsigned int u0[W], u1[W], u2[W], u3[W];
        ldrow<W>(h, (size_t)p0.x, F, lane, u0);
        ldrow<W>(h, (size_t)p1.x, F, lane, u1);
        ldrow<W>(h, (size_t)p2.x, F, lane, u2);
        ldrow<W>(h, (size_t)p3.x, F, lane, u3);
        fmarow<W>(u0, __int_as_float(p0.y), acc);
        fmarow<W>(u1, __int_as_float(p1.y), acc);
        fmarow<W>(u2, __int_as_float(p2.y), acc);
        fmarow<W>(u3, __int_as_float(p3.y), acc);
    }
    for (; j < e1; ++j) {
        i32x2 p0 = pairs[j];
        unsigned int u0[W];
        ldrow<W>(h, (size_t)p0.x, F, lane, u0);
        fmarow<W>(u0, __int_as_float(p0.y), acc);
    }
    const float* bp = biasf + lane * FPL;
    const float* wp = w5f + lane * FPL;
    float partial = 0.f;
#pragma unroll
    for (int k = 0; k < FPL; ++k)
        partial += fmaxf(acc[k] + bp[k], 0.f) * wp[k];
#pragma unroll
    for (int off = 32; off > 0; off >>= 1)
        partial += __shfl_xor(partial, off);
    if (lane == 0) h5[node] = partial;
}

// ---------- final scalar aggregate, write output in harness dtype ----------
__global__ void k_final(const float* __restrict__ h5, const int* __restrict__ rowptr,
                        const int* __restrict__ csr_pair,
                        const float* __restrict__ selfnorm,
                        const void* __restrict__ b5, const int* __restrict__ flagp,
                        void* __restrict__ out) {
    bool bf = (*flagp != 0);
    int i = blockIdx.x * blockDim.x + threadIdx.x;
    if (i >= N_NODES) return;
    float acc = selfnorm[i] * h5[i];
    int e0 = rowptr[i], e1 = rowptr[i + 1];
    for (int j = e0; j < e1; ++j) {
        int s = csr_pair[2 * (size_t)j];
        float w = __int_as_float(csr_pair[2 * (size_t)j + 1]);
        acc += w * h5[s];
    }
    acc += ldF(b5, 0, bf);
    if (bf) ((unsigned short*)out)[i] = f2bf(acc);
    else    ((float*)out)[i] = acc;
}

extern "C" void kernel_launch(void* const* d_in, const int* in_sizes, int n_in,
                              void* d_out, int out_size, void* d_ws, size_t ws_size,
                              hipStream_t stream) {
    const void* x  = d_in[0];
    const int*  ei = (const int*)d_in[1];
    const void* ea = d_in[2];
    const void* W1 = d_in[3];
    const void* b1 = d_in[4];
    const void* W2 = d_in[5];
    const void* b2 = d_in[6];
    const void* W3 = d_in[7];
    const void* b3 = d_in[8];
    const void* W4 = d_in[9];
    const void* b4 = d_in[10];
    const void* W5 = d_in[11];
    const void* b5 = d_in[12];

    char* ws = (char*)d_ws;
    size_t off = 0;
    auto take = [&](size_t bytes) -> void* {
        off = (off + 255) & ~(size_t)255;
        void* p = ws + off;
        off += bytes;
        return p;
    };
    int*   flagp    = (int*)take(2 * sizeof(int));
    float* deg      = (float*)take(N_NODES * sizeof(float));
    int*   counts   = (int*)take(N_NODES * sizeof(int));
    int*   fill     = (int*)take(N_NODES * sizeof(int));
    size_t zspan    = (size_t)((char*)(fill + N_NODES) - (char*)deg);
    float* dinv     = (float*)take(N_NODES * sizeof(float));
    float* selfnorm = (float*)take(N_NODES * sizeof(float));
    float* h5       = (float*)take(N_NODES * sizeof(float));
    float* biasf    = (float*)take(2304 * sizeof(float));  // 4x512 biases + 256 W5
    int*   bsum     = (int*)take(128 * sizeof(int));
    int*   bofs     = (int*)take(128 * sizeof(int));
    int*   rowptr   = (int*)take((N_NODES + 1) * sizeof(int));
    int*   csr_pair = (int*)take((size_t)N_EDGES * 2 * sizeof(int));  // (src, normbits)
    unsigned short* Wp = (unsigned short*)take((size_t)114688 * 8 * sizeof(unsigned short));
    unsigned short* P  = (unsigned short*)take((size_t)MPAD * 512 * sizeof(unsigned short));
    unsigned short* H  = (unsigned short*)take((size_t)MPAD * 512 * sizeof(unsigned short));

    (void)hipMemsetAsync(deg, 0, zspan, stream);

    const int EB = (N_EDGES + 255) / 256;
    const int NB = (N_NODES + 255) / 256;  // 79 == NBLK
    const int AGW = N_NODES * 4;  // 4 chunks per node (R7 winner)

    k_detect<<<1, 64, 0, stream>>>((const unsigned int*)x, ei, flagp);
    k_canon_deg<<<EB, 256, 0, stream>>>(ei, ea, flagp, deg, counts);
    k_part<<<NB, 256, 0, stream>>>(counts, deg, dinv, selfnorm, bsum);
    k_scanb<<<1, 128, 0, stream>>>(bsum, bofs, rowptr);
    k_row<<<NB, 256, 0, stream>>>(counts, bofs, rowptr);
    k_csr<<<EB, 256, 0, stream>>>(ei, ea, flagp, dinv, rowptr, fill, csr_pair);

    k_prep<<<457, 256, 0, stream>>>(W1, W2, W3, W4, b1, b2, b3, b4, W5, flagp,
                                    Wp, biasf);

    const int MB128 = (N_NODES + 127) / 128;  // 157

    k_gemm_mfma<<<dim3(MB128, 4), 256, 0, stream>>>(P, x, flagp, 1,
                                                    Wp, H, N_NODES, 512, 512);
    k_agg_w<<<AGW, 64, 0, stream>>>(H, rowptr, csr_pair, selfnorm, biasf, P);
    k_gemm_mfma<<<dim3(MB128, 4), 256, 0, stream>>>(P, x, flagp, 0,
                                                    Wp + (size_t)32768 * 8, H,
                                                    N_NODES, 512, 512);
    k_agg_w<<<AGW, 64, 0, stream>>>(H, rowptr, csr_pair, selfnorm, biasf + 512, P);
    k_gemm_mfma<<<dim3(MB128, 4), 256, 0, stream>>>(P, x, flagp, 0,
                                                    Wp + (size_t)65536 * 8, H,
                                                    N_NODES, 512, 512);
    k_agg_w<<<AGW, 64, 0, stream>>>(H, rowptr, csr_pair, selfnorm, biasf + 1024, P);
    k_gemm_mfma<<<dim3(MB128, 2), 256, 0, stream>>>(P, x, flagp, 0,
                                                    Wp + (size_t)98304 * 8, H,
                                                    N_NODES, 512, 256);
    k_agg_fuse<<<N_NODES, 64, 0, stream>>>(H, rowptr, csr_pair, selfnorm,
                                           biasf + 1536, biasf + 2048, h5);

    k_final<<<NB, 256, 0, stream>>>(h5, rowptr, csr_pair, selfnorm, b5, flagp,
                                    d_out);
}

// Round 12
// 431.877 us; speedup vs baseline: 1.1111x; 1.0050x over previous
//
#include <hip/hip_runtime.h>
#include <cstdint>
#include <cstddef>

#define N_NODES 20000
#define N_EDGES 400000
#define NBLK 79  // ceil(20000/256)
#define MPAD 20128  // N_NODES rounded up to 128-row tiles

typedef __attribute__((ext_vector_type(8))) short bf16x8;
typedef __attribute__((ext_vector_type(4))) float f32x4;
typedef __attribute__((ext_vector_type(2))) int i32x2;

// ---------- bf16 helpers (manual, bit-exact) ----------
__device__ __forceinline__ float bf2f(unsigned short u) {
    return __uint_as_float(((unsigned int)u) << 16);
}
__device__ __forceinline__ unsigned short f2bf(float f) {
    unsigned int x = __float_as_uint(f);
    unsigned int lsb = (x >> 16) & 1u;
    x += 0x7fffu + lsb;  // round-to-nearest-even
    return (unsigned short)(x >> 16);
}

// ---------- flag-aware loads for harness float tensors (bf16 or fp32) ----------
__device__ __forceinline__ float ldF(const void* p, size_t i, bool bf) {
    return bf ? bf2f(((const unsigned short*)p)[i]) : ((const float*)p)[i];
}

// ---------- async global->LDS 16B copy ----------
__device__ __forceinline__ void gl2lds16(const unsigned short* g, unsigned short* l) {
    __builtin_amdgcn_global_load_lds(
        (const __attribute__((address_space(1))) void*)g,
        (__attribute__((address_space(3))) void*)l, 16, 0, 0);
}

// ---------- dtype + int64 detection (one wave, lane-parallel) ----------
__global__ void k_detect(const unsigned int* __restrict__ xw, const int* __restrict__ raw,
                         int* __restrict__ flag) {
    int lane = threadIdx.x;
    int cnt = 0, nz = 0;
    for (int i = lane; i < 256; i += 64) {
        unsigned short lo = (unsigned short)(xw[i] & 0xffffu);
        int e = (lo >> 7) & 0xff;
        if (e >= 110 && e <= 135) cnt++;
    }
    for (int i = 2 * lane + 1; i < 512; i += 128)
        if (raw[i] != 0) nz++;
#pragma unroll
    for (int off = 32; off > 0; off >>= 1) {
        cnt += __shfl_down(cnt, off);
        nz  += __shfl_down(nz, off);
    }
    if (lane == 0) {
        flag[0] = (cnt >= 128) ? 1 : 0;  // 1 = float tensors are bf16
        flag[1] = (nz == 0) ? 1 : 0;     // 1 = edge_index is raw int64
    }
}

// ---------- degree + counts (reads raw edge_index directly) ----------
__global__ void k_canon_deg(const int* __restrict__ raw, const void* __restrict__ ew,
                            const int* __restrict__ flagp,
                            float* __restrict__ deg, int* __restrict__ counts) {
    bool bf = (flagp[0] != 0);
    int is64 = flagp[1];
    int e = blockIdx.x * blockDim.x + threadIdx.x;
    if (e >= N_EDGES) return;
    int d;
    if (is64) d = raw[2 * (N_EDGES + e)];
    else      d = raw[N_EDGES + e];
    atomicAdd(&deg[d], ldF(ew, e, bf));
    atomicAdd(&counts[d], 1);
}

// ---------- pass 1: per-block count sums + fused dinv/selfnorm ----------
__global__ __launch_bounds__(256) void k_part(const int* __restrict__ counts,
                                              const float* __restrict__ deg,
                                              float* __restrict__ dinv,
                                              float* __restrict__ selfnorm,
                                              int* __restrict__ bsum) {
    __shared__ int s[256];
    int t = threadIdx.x;
    int i = blockIdx.x * 256 + t;
    int c = (i < N_NODES) ? counts[i] : 0;
    if (i < N_NODES) {
        float d = deg[i] + 1.0f;
        float r = rsqrtf(d);
        dinv[i] = r;
        selfnorm[i] = r * r;
    }
    s[t] = c;
    __syncthreads();
    for (int off = 128; off > 0; off >>= 1) {
        if (t < off) s[t] += s[t + off];
        __syncthreads();
    }
    if (t == 0) bsum[blockIdx.x] = s[0];
}

// ---------- pass 2: exclusive scan of 79 block sums (1 tiny block) ----------
__global__ void k_scanb(const int* __restrict__ bsum, int* __restrict__ bofs,
                        int* __restrict__ rowptr) {
    __shared__ int s[128];
    int t = threadIdx.x;
    int v = (t < NBLK) ? bsum[t] : 0;
    s[t] = v;
    __syncthreads();
    for (int off = 1; off < 128; off <<= 1) {
        int u = (t >= off) ? s[t - off] : 0;
        __syncthreads();
        s[t] += u;
        __syncthreads();
    }
    if (t < NBLK) bofs[t] = s[t] - v;  // exclusive
    if (t == NBLK - 1) rowptr[N_NODES] = s[t];
}

// ---------- pass 3: intra-block scan + block offset -> rowptr ----------
__global__ __launch_bounds__(256) void k_row(const int* __restrict__ counts,
                                             const int* __restrict__ bofs,
                                             int* __restrict__ rowptr) {
    __shared__ int s[256];
    int t = threadIdx.x;
    int b = blockIdx.x;
    int i = b * 256 + t;
    int c = (i < N_NODES) ? counts[i] : 0;
    s[t] = c;
    __syncthreads();
    for (int off = 1; off < 256; off <<= 1) {
        int u = (t >= off) ? s[t - off] : 0;
        __syncthreads();
        s[t] += u;
        __syncthreads();
    }
    if (i < N_NODES) rowptr[i] = bofs[b] + s[t] - c;
}

// ---------- scatter edges into CSR-by-dst: packed (src, norm) pairs ----------
__global__ void k_csr(const int* __restrict__ raw, const void* __restrict__ ew,
                      const int* __restrict__ flagp,
                      const float* __restrict__ dinv, const int* __restrict__ rowptr,
                      int* __restrict__ fill, int* __restrict__ csr_pair) {
    bool bf = (flagp[0] != 0);
    int is64 = flagp[1];
    int e = blockIdx.x * blockDim.x + threadIdx.x;
    if (e >= N_EDGES) return;
    int s, d;
    if (is64) { s = raw[2 * e]; d = raw[2 * (N_EDGES + e)]; }
    else      { s = raw[e];     d = raw[N_EDGES + e]; }
    int p = rowptr[d] + atomicAdd(&fill[d], 1);
    float nrm = dinv[s] * ldF(ew, e, bf) * dinv[d];
    i32x2 pv;
    pv.x = s;
    pv.y = __float_as_int(nrm);
    *(i32x2*)(csr_pair + 2 * (size_t)p) = pv;
}

// ---------- prep: pack weights | cast biases + W5 -> fp32 (457 blocks) ----------
__global__ __launch_bounds__(256) void k_prep(const void* __restrict__ W1,
                                              const void* __restrict__ W2,
                                              const void* __restrict__ W3,
                                              const void* __restrict__ W4,
                                              const void* __restrict__ b1,
                                              const void* __restrict__ b2,
                                              const void* __restrict__ b3,
                                              const void* __restrict__ b4,
                                              const void* __restrict__ W5,
                                              const int* __restrict__ flagp,
                                              unsigned short* __restrict__ Wp,
                                              float* __restrict__ biasf) {
    bool bf = (*flagp != 0);
    int b = blockIdx.x;
    int t = threadIdx.x;
    if (b < 448) {
        int gidx = b * 256 + t;  // < 114688 exactly
        const void* W;
        int idx = gidx, N, nbl;
        if (gidx < 32768)      { W = W1; N = 512; nbl = 5; }
        else if (gidx < 65536) { W = W2; N = 512; nbl = 5; idx -= 32768; }
        else if (gidx < 98304) { W = W3; N = 512; nbl = 5; idx -= 65536; }
        else                   { W = W4; N = 256; nbl = 4; idx -= 98304; }
        int lane = idx & 63;
        int blk = idx >> 6;
        int nb = blk & ((1 << nbl) - 1);
        int kb = blk >> nbl;
        int n = (nb << 4) + (lane & 15);
        int kbase = (kb << 5) + ((lane >> 4) << 3);
        unsigned short o[8];
#pragma unroll
        for (int j = 0; j < 8; ++j)
            o[j] = f2bf(ldF(W, (size_t)(kbase + j) * N + n, bf));
        *(uint4*)(&Wp[(size_t)gidx * 8]) = *(const uint4*)o;
    } else {
        int i = (b - 448) * 256 + t;
        if (i >= 2304) return;
        if (i < 2048) {
            int L = i >> 9, r = i & 511;
            if (L == 3 && r >= 256) return;
            const void* bb = (L == 0) ? b1 : (L == 1) ? b2 : (L == 2) ? b3 : b4;
            biasf[i] = ldF(bb, r, bf);
        } else {
            biasf[i] = ldF(W5, i - 2048, bf);  // fp32 W5 at biasf[2048..2303]
        }
    }
}

// ---------- MFMA bf16 GEMM, 128x128 tile, BK=64, XCD-pinned 1D grid ----------
// Grid mapping: xcd = bid&7, t = bid>>3, xrow = xcd*rpx + t/nty, ycol = t%nty.
// Each XCD owns ~20 contiguous row-tiles (A panel 2.56 MB -> L2-resident) and
// runs all col-tiles of a row-tile back-to-back -> A fetched from HBM once
// (R11 profile: FETCH 82 MB = 4x A re-read because dim3(157,4) spread the same
// row-tile across XCDs). B (<=0.5 MB) trivially resident.
__global__ __launch_bounds__(256) void k_gemm_mfma(const unsigned short* __restrict__ Abase,
                                                   const void* __restrict__ Xraw,
                                                   const int* __restrict__ flagp,
                                                   int useX,
                                                   const unsigned short* __restrict__ Bp,
                                                   unsigned short* __restrict__ C,
                                                   int M, int K, int N) {
    const int AP = 72;  // A-tile row stride (64 + 8 pad) shorts -> 2-way-max banks
    __shared__ __align__(16) unsigned short As[128 * AP];  // 18432 B
    __shared__ __align__(16) unsigned short Bs[2 * 8 * 512];  // 16384 B
    bool bf = (*flagp != 0);
    bool cvt = useX && !bf;  // fp32 x -> convert in staging
    const unsigned short* A = useX ? (const unsigned short*)Xraw : Abase;
    const float* Af = (const float*)Xraw;

    int mt = (M + 127) >> 7;        // row tiles (157)
    int rpx = (mt + 7) >> 3;        // row tiles per XCD (20)
    int nty = N >> 7;               // col tiles (4 or 2)
    int xcd = blockIdx.x & 7;
    int t = blockIdx.x >> 3;
    int trow = t / nty;
    int ycol = t - trow * nty;
    int xrow = xcd * rpx + trow;
    if (xrow >= mt) return;
    int row0 = xrow << 7;
    int col0 = ycol << 7;

    int tid = threadIdx.x;
    int lane = tid & 63;
    int wave = tid >> 6;
    int wr = wave >> 1, wc = wave & 1;
    int nbt = N >> 4;
    int q = lane >> 4;
    int mm = lane & 15;

    f32x4 acc[4][4] = {};

    for (int kb2 = 0; kb2 < (K >> 6); ++kb2) {
        const unsigned short* breg0 = Bp + (((size_t)(2 * kb2) * nbt + (col0 >> 4)) << 9);
        const unsigned short* breg1 = Bp + (((size_t)(2 * kb2 + 1) * nbt + (col0 >> 4)) << 9);
        gl2lds16(breg0 + (size_t)tid * 8, &Bs[(size_t)tid * 8]);
        gl2lds16(breg0 + (size_t)(tid + 256) * 8, &Bs[(size_t)(tid + 256) * 8]);
        gl2lds16(breg1 + (size_t)tid * 8, &Bs[4096 + (size_t)tid * 8]);
        gl2lds16(breg1 + (size_t)(tid + 256) * 8, &Bs[4096 + (size_t)(tid + 256) * 8]);
#pragma unroll
        for (int i = 0; i < 4; ++i) {
            int c = tid + i * 256;
            int row = c >> 3, kq = c & 7;
            int grow = min(row0 + row, M - 1);  // clamp: x is unpadded
            size_t idx = (size_t)grow * K + (kb2 << 6) + (kq << 3);
            if (!cvt) {
                uint4 v = *(const uint4*)(&A[idx]);
                *(uint4*)(&As[row * AP + (kq << 3)]) = v;
            } else {
                float4 v0 = *(const float4*)(Af + idx);
                float4 v1 = *(const float4*)(Af + idx + 4);
                uint4 o;
                o.x = (unsigned int)f2bf(v0.x) | ((unsigned int)f2bf(v0.y) << 16);
                o.y = (unsigned int)f2bf(v0.z) | ((unsigned int)f2bf(v0.w) << 16);
                o.z = (unsigned int)f2bf(v1.x) | ((unsigned int)f2bf(v1.y) << 16);
                o.w = (unsigned int)f2bf(v1.z) | ((unsigned int)f2bf(v1.w) << 16);
                *(uint4*)(&As[row * AP + (kq << 3)]) = o;
            }
        }
        __syncthreads();
#pragma unroll
        for (int kk = 0; kk < 2; ++kk) {
            bf16x8 af[4], bfr[4];
#pragma unroll
            for (int mb = 0; mb < 4; ++mb)
                af[mb] = *(const bf16x8*)(&As[(wr * 64 + mb * 16 + mm) * AP + kk * 32 + q * 8]);
#pragma unroll
            for (int nb = 0; nb < 4; ++nb)
                bfr[nb] = *(const bf16x8*)(&Bs[kk * 4096 + ((wc * 4 + nb) * 64 + lane) * 8]);
#pragma unroll
            for (int mb = 0; mb < 4; ++mb)
#pragma unroll
                for (int nb = 0; nb < 4; ++nb)
                    acc[mb][nb] = __builtin_amdgcn_mfma_f32_16x16x32_bf16(
                        af[mb], bfr[nb], acc[mb][nb], 0, 0, 0);
        }
        __syncthreads();
    }
#pragma unroll
    for (int mb = 0; mb < 4; ++mb) {
#pragma unroll
        for (int r = 0; r < 4; ++r) {
            int grow = row0 + wr * 64 + mb * 16 + q * 4 + r;
            if (grow < M) {
#pragma unroll
                for (int nb = 0; nb < 4; ++nb) {
                    int gcol = col0 + wc * 64 + nb * 16 + mm;
                    C[(size_t)grow * N + gcol] = f2bf(acc[mb][nb][r]);
                }
            }
        }
    }
}

// ---------- row-load + fma helpers for the gather ----------
template <int W>
__device__ __forceinline__ void ldrow(const unsigned short* h, size_t row, int F, int lane,
                                      unsigned int* u) {
    const unsigned int* p = (const unsigned int*)(h + row * F) + lane * W;
    if constexpr (W == 4) {
        uint4 v = *(const uint4*)p; u[0] = v.x; u[1] = v.y; u[2] = v.z; u[3] = v.w;
    } else {
        uint2 v = *(const uint2*)p; u[0] = v.x; u[1] = v.y;
    }
}
template <int W>
__device__ __forceinline__ void fmarow(const unsigned int* u, float w, float* acc) {
#pragma unroll
    for (int k = 0; k < W; ++k) {
        acc[2 * k]     = fmaf(bf2f((unsigned short)(u[k] & 0xffffu)), w, acc[2 * k]);
        acc[2 * k + 1] = fmaf(bf2f((unsigned short)(u[k] >> 16)),     w, acc[2 * k + 1]);
    }
}

// ---------- 4-chunk XCD-pinned wave-per-node aggregate (F=512) ----------
// Byte-exact round-7 winner: 42.8 us, FETCH 90 MB, delivered ~10 TB/s.
__global__ __launch_bounds__(64) void k_agg_w(const unsigned short* __restrict__ h,
                                              const int* __restrict__ rowptr,
                                              const int* __restrict__ csr_pair,
                                              const float* __restrict__ selfnorm,
                                              const float* __restrict__ biasf,
                                              unsigned short* __restrict__ out) {
    constexpr int F = 512;
    int lane = threadIdx.x;
    int chunk = blockIdx.x & 3;
    int node = blockIdx.x >> 2;
    int e0 = rowptr[node], e1 = rowptr[node + 1];
    float sn = selfnorm[node];
    const unsigned short* hb = h + chunk * 128 + lane * 2;  // this lane's dword column

    float a0, a1;
    {
        unsigned int u = *(const unsigned int*)(hb + (size_t)node * F);
        a0 = sn * bf2f((unsigned short)(u & 0xffffu));
        a1 = sn * bf2f((unsigned short)(u >> 16));
    }
    const i32x2* pairs = (const i32x2*)csr_pair;
    int j = e0;
    for (; j + 7 < e1; j += 8) {
        i32x2 p0 = pairs[j],     p1 = pairs[j + 1], p2 = pairs[j + 2], p3 = pairs[j + 3];
        i32x2 p4 = pairs[j + 4], p5 = pairs[j + 5], p6 = pairs[j + 6], p7 = pairs[j + 7];
        unsigned int u0 = *(const unsigned int*)(hb + (size_t)p0.x * F);
        unsigned int u1 = *(const unsigned int*)(hb + (size_t)p1.x * F);
        unsigned int u2 = *(const unsigned int*)(hb + (size_t)p2.x * F);
        unsigned int u3 = *(const unsigned int*)(hb + (size_t)p3.x * F);
        unsigned int u4 = *(const unsigned int*)(hb + (size_t)p4.x * F);
        unsigned int u5 = *(const unsigned int*)(hb + (size_t)p5.x * F);
        unsigned int u6 = *(const unsigned int*)(hb + (size_t)p6.x * F);
        unsigned int u7 = *(const unsigned int*)(hb + (size_t)p7.x * F);
        float w0 = __int_as_float(p0.y), w1 = __int_as_float(p1.y);
        float w2 = __int_as_float(p2.y), w3 = __int_as_float(p3.y);
        float w4 = __int_as_float(p4.y), w5 = __int_as_float(p5.y);
        float w6 = __int_as_float(p6.y), w7 = __int_as_float(p7.y);
        a0 = fmaf(bf2f((unsigned short)(u0 & 0xffffu)), w0, a0);
        a1 = fmaf(bf2f((unsigned short)(u0 >> 16)),     w0, a1);
        a0 = fmaf(bf2f((unsigned short)(u1 & 0xffffu)), w1, a0);
        a1 = fmaf(bf2f((unsigned short)(u1 >> 16)),     w1, a1);
        a0 = fmaf(bf2f((unsigned short)(u2 & 0xffffu)), w2, a0);
        a1 = fmaf(bf2f((unsigned short)(u2 >> 16)),     w2, a1);
        a0 = fmaf(bf2f((unsigned short)(u3 & 0xffffu)), w3, a0);
        a1 = fmaf(bf2f((unsigned short)(u3 >> 16)),     w3, a1);
        a0 = fmaf(bf2f((unsigned short)(u4 & 0xffffu)), w4, a0);
        a1 = fmaf(bf2f((unsigned short)(u4 >> 16)),     w4, a1);
        a0 = fmaf(bf2f((unsigned short)(u5 & 0xffffu)), w5, a0);
        a1 = fmaf(bf2f((unsigned short)(u5 >> 16)),     w5, a1);
        a0 = fmaf(bf2f((unsigned short)(u6 & 0xffffu)), w6, a0);
        a1 = fmaf(bf2f((unsigned short)(u6 >> 16)),     w6, a1);
        a0 = fmaf(bf2f((unsigned short)(u7 & 0xffffu)), w7, a0);
        a1 = fmaf(bf2f((unsigned short)(u7 >> 16)),     w7, a1);
    }
    for (; j + 3 < e1; j += 4) {
        i32x2 p0 = pairs[j], p1 = pairs[j + 1], p2 = pairs[j + 2], p3 = pairs[j + 3];
        unsigned int u0 = *(const unsigned int*)(hb + (size_t)p0.x * F);
        unsigned int u1 = *(const unsigned int*)(hb + (size_t)p1.x * F);
        unsigned int u2 = *(const unsigned int*)(hb + (size_t)p2.x * F);
        unsigned int u3 = *(const unsigned int*)(hb + (size_t)p3.x * F);
        float w0 = __int_as_float(p0.y), w1 = __int_as_float(p1.y);
        float w2 = __int_as_float(p2.y), w3 = __int_as_float(p3.y);
        a0 = fmaf(bf2f((unsigned short)(u0 & 0xffffu)), w0, a0);
        a1 = fmaf(bf2f((unsigned short)(u0 >> 16)),     w0, a1);
        a0 = fmaf(bf2f((unsigned short)(u1 & 0xffffu)), w1, a0);
        a1 = fmaf(bf2f((unsigned short)(u1 >> 16)),     w1, a1);
        a0 = fmaf(bf2f((unsigned short)(u2 & 0xffffu)), w2, a0);
        a1 = fmaf(bf2f((unsigned short)(u2 >> 16)),     w2, a1);
        a0 = fmaf(bf2f((unsigned short)(u3 & 0xffffu)), w3, a0);
        a1 = fmaf(bf2f((unsigned short)(u3 >> 16)),     w3, a1);
    }
    for (; j < e1; ++j) {
        i32x2 p0 = pairs[j];
        unsigned int u0 = *(const unsigned int*)(hb + (size_t)p0.x * F);
        float w0 = __int_as_float(p0.y);
        a0 = fmaf(bf2f((unsigned short)(u0 & 0xffffu)), w0, a0);
        a1 = fmaf(bf2f((unsigned short)(u0 >> 16)),     w0, a1);
    }
    {
        const float* bp = biasf + chunk * 128 + lane * 2;
        a0 = fmaxf(a0 + bp[0], 0.f);
        a1 = fmaxf(a1 + bp[1], 0.f);
        unsigned int o = (unsigned int)f2bf(a0) | ((unsigned int)f2bf(a1) << 16);
        *(unsigned int*)(out + (size_t)node * F + chunk * 128 + lane * 2) = o;
    }
}

// ---------- L4 agg fused with L5 GEMV: whole-row (F=256), 1-wave blocks ----------
__global__ __launch_bounds__(64) void k_agg_fuse(const unsigned short* __restrict__ h,
                                                 const int* __restrict__ rowptr,
                                                 const int* __restrict__ csr_pair,
                                                 const float* __restrict__ selfnorm,
                                                 const float* __restrict__ biasf,
                                                 const float* __restrict__ w5f,
                                                 float* __restrict__ h5) {
    constexpr int F = 256, FPL = 4, W = 2;
    int lane = threadIdx.x;
    int node = blockIdx.x;
    int e0 = rowptr[node], e1 = rowptr[node + 1];
    float sn = selfnorm[node];

    float acc[FPL];
    {
        unsigned int u[W];
        ldrow<W>(h, (size_t)node, F, lane, u);
#pragma unroll
        for (int k = 0; k < W; ++k) {
            acc[2 * k]     = sn * bf2f((unsigned short)(u[k] & 0xffffu));
            acc[2 * k + 1] = sn * bf2f((unsigned short)(u[k] >> 16));
        }
    }
    const i32x2* pairs = (const i32x2*)csr_pair;
    int j = e0;
    for (; j + 7 < e1; j += 8) {
        i32x2 p0 = pairs[j],     p1 = pairs[j + 1], p2 = pairs[j + 2], p3 = pairs[j + 3];
        i32x2 p4 = pairs[j + 4], p5 = pairs[j + 5], p6 = pairs[j + 6], p7 = pairs[j + 7];
        unsigned int u0[W], u1[W], u2[W], u3[W], u4[W], u5[W], u6[W], u7[W];
        ldrow<W>(h, (size_t)p0.x, F, lane, u0);
        ldrow<W>(h, (size_t)p1.x, F, lane, u1);
        ldrow<W>(h, (size_t)p2.x, F, lane, u2);
        ldrow<W>(h, (size_t)p3.x, F, lane, u3);
        ldrow<W>(h, (size_t)p4.x, F, lane, u4);
        ldrow<W>(h, (size_t)p5.x, F, lane, u5);
        ldrow<W>(h, (size_t)p6.x, F, lane, u6);
        ldrow<W>(h, (size_t)p7.x, F, lane, u7);
        fmarow<W>(u0, __int_as_float(p0.y), acc);
        fmarow<W>(u1, __int_as_float(p1.y), acc);
        fmarow<W>(u2, __int_as_float(p2.y), acc);
        fmarow<W>(u3, __int_as_float(p3.y), acc);
        fmarow<W>(u4, __int_as_float(p4.y), acc);
        fmarow<W>(u5, __int_as_float(p5.y), acc);
        fmarow<W>(u6, __int_as_float(p6.y), acc);
        fmarow<W>(u7, __int_as_float(p7.y), acc);
    }
    for (; j + 3 < e1; j += 4) {
        i32x2 p0 = pairs[j], p1 = pairs[j + 1], p2 = pairs[j + 2], p3 = pairs[j + 3];
        unsigned int u0[W], u1[W], u2[W], u3[W];
        ldrow<W>(h, (size_t)p0.x, F, lane, u0);
        ldrow<W>(h, (size_t)p1.x, F, lane, u1);
        ldrow<W>(h, (size_t)p2.x, F, lane, u2);
        ldrow<W>(h, (size_t)p3.x, F, lane, u3);
        fmarow<W>(u0, __int_as_float(p0.y), acc);
        fmarow<W>(u1, __int_as_float(p1.y), acc);
        fmarow<W>(u2, __int_as_float(p2.y), acc);
        fmarow<W>(u3, __int_as_float(p3.y), acc);
    }
    for (; j < e1; ++j) {
        i32x2 p0 = pairs[j];
        unsigned int u0[W];
        ldrow<W>(h, (size_t)p0.x, F, lane, u0);
        fmarow<W>(u0, __int_as_float(p0.y), acc);
    }
    const float* bp = biasf + lane * FPL;
    const float* wp = w5f + lane * FPL;
    float partial = 0.f;
#pragma unroll
    for (int k = 0; k < FPL; ++k)
        partial += fmaxf(acc[k] + bp[k], 0.f) * wp[k];
#pragma unroll
    for (int off = 32; off > 0; off >>= 1)
        partial += __shfl_xor(partial, off);
    if (lane == 0) h5[node] = partial;
}

// ---------- final scalar aggregate, write output in harness dtype ----------
__global__ void k_final(const float* __restrict__ h5, const int* __restrict__ rowptr,
                        const int* __restrict__ csr_pair,
                        const float* __restrict__ selfnorm,
                        const void* __restrict__ b5, const int* __restrict__ flagp,
                        void* __restrict__ out) {
    bool bf = (*flagp != 0);
    int i = blockIdx.x * blockDim.x + threadIdx.x;
    if (i >= N_NODES) return;
    float acc = selfnorm[i] * h5[i];
    int e0 = rowptr[i], e1 = rowptr[i + 1];
    for (int j = e0; j < e1; ++j) {
        int s = csr_pair[2 * (size_t)j];
        float w = __int_as_float(csr_pair[2 * (size_t)j + 1]);
        acc += w * h5[s];
    }
    acc += ldF(b5, 0, bf);
    if (bf) ((unsigned short*)out)[i] = f2bf(acc);
    else    ((float*)out)[i] = acc;
}

extern "C" void kernel_launch(void* const* d_in, const int* in_sizes, int n_in,
                              void* d_out, int out_size, void* d_ws, size_t ws_size,
                              hipStream_t stream) {
    const void* x  = d_in[0];
    const int*  ei = (const int*)d_in[1];
    const void* ea = d_in[2];
    const void* W1 = d_in[3];
    const void* b1 = d_in[4];
    const void* W2 = d_in[5];
    const void* b2 = d_in[6];
    const void* W3 = d_in[7];
    const void* b3 = d_in[8];
    const void* W4 = d_in[9];
    const void* b4 = d_in[10];
    const void* W5 = d_in[11];
    const void* b5 = d_in[12];

    char* ws = (char*)d_ws;
    size_t off = 0;
    auto take = [&](size_t bytes) -> void* {
        off = (off + 255) & ~(size_t)255;
        void* p = ws + off;
        off += bytes;
        return p;
    };
    int*   flagp    = (int*)take(2 * sizeof(int));
    float* deg      = (float*)take(N_NODES * sizeof(float));
    int*   counts   = (int*)take(N_NODES * sizeof(int));
    int*   fill     = (int*)take(N_NODES * sizeof(int));
    size_t zspan    = (size_t)((char*)(fill + N_NODES) - (char*)deg);
    float* dinv     = (float*)take(N_NODES * sizeof(float));
    float* selfnorm = (float*)take(N_NODES * sizeof(float));
    float* h5       = (float*)take(N_NODES * sizeof(float));
    float* biasf    = (float*)take(2304 * sizeof(float));  // 4x512 biases + 256 W5
    int*   bsum     = (int*)take(128 * sizeof(int));
    int*   bofs     = (int*)take(128 * sizeof(int));
    int*   rowptr   = (int*)take((N_NODES + 1) * sizeof(int));
    int*   csr_pair = (int*)take((size_t)N_EDGES * 2 * sizeof(int));  // (src, normbits)
    unsigned short* Wp = (unsigned short*)take((size_t)114688 * 8 * sizeof(unsigned short));
    unsigned short* P  = (unsigned short*)take((size_t)MPAD * 512 * sizeof(unsigned short));
    unsigned short* H  = (unsigned short*)take((size_t)MPAD * 512 * sizeof(unsigned short));

    (void)hipMemsetAsync(deg, 0, zspan, stream);

    const int EB = (N_EDGES + 255) / 256;
    const int NB = (N_NODES + 255) / 256;  // 79 == NBLK
    const int AGW = N_NODES * 4;  // 4 chunks per node (R7 winner)

    k_detect<<<1, 64, 0, stream>>>((const unsigned int*)x, ei, flagp);
    k_canon_deg<<<EB, 256, 0, stream>>>(ei, ea, flagp, deg, counts);
    k_part<<<NB, 256, 0, stream>>>(counts, deg, dinv, selfnorm, bsum);
    k_scanb<<<1, 128, 0, stream>>>(bsum, bofs, rowptr);
    k_row<<<NB, 256, 0, stream>>>(counts, bofs, rowptr);
    k_csr<<<EB, 256, 0, stream>>>(ei, ea, flagp, dinv, rowptr, fill, csr_pair);

    k_prep<<<457, 256, 0, stream>>>(W1, W2, W3, W4, b1, b2, b3, b4, W5, flagp,
                                    Wp, biasf);

    const int MT = (N_NODES + 127) / 128;   // 157 row tiles
    const int RPX = (MT + 7) / 8;           // 20 row tiles per XCD
    const int G512 = 8 * RPX * 4;           // 640 blocks (N=512)
    const int G256 = 8 * RPX * 2;           // 320 blocks (N=256)

    k_gemm_mfma<<<G512, 256, 0, stream>>>(P, x, flagp, 1,
                                          Wp, H, N_NODES, 512, 512);
    k_agg_w<<<AGW, 64, 0, stream>>>(H, rowptr, csr_pair, selfnorm, biasf, P);
    k_gemm_mfma<<<G512, 256, 0, stream>>>(P, x, flagp, 0,
                                          Wp + (size_t)32768 * 8, H,
                                          N_NODES, 512, 512);
    k_agg_w<<<AGW, 64, 0, stream>>>(H, rowptr, csr_pair, selfnorm, biasf + 512, P);
    k_gemm_mfma<<<G512, 256, 0, stream>>>(P, x, flagp, 0,
                                          Wp + (size_t)65536 * 8, H,
                                          N_NODES, 512, 512);
    k_agg_w<<<AGW, 64, 0, stream>>>(H, rowptr, csr_pair, selfnorm, biasf + 1024, P);
    k_gemm_mfma<<<G256, 256, 0, stream>>>(P, x, flagp, 0,
                                          Wp + (size_t)98304 * 8, H,
                                          N_NODES, 512, 256);
    k_agg_fuse<<<N_NODES, 64, 0, stream>>>(H, rowptr, csr_pair, selfnorm,
                                           biasf + 1536, biasf + 2048, h5);

    k_final<<<NB, 256, 0, stream>>>(h5, rowptr, csr_pair, selfnorm, b5, flagp,
                                    d_out);
}

// Round 13
// 408.246 us; speedup vs baseline: 1.1755x; 1.0579x over previous
//
#include <hip/hip_runtime.h>
#include <cstdint>
#include <cstddef>

#define N_NODES 20000
#define N_EDGES 400000
#define NBLK 79  // ceil(20000/256)
#define MPAD 20128  // N_NODES rounded up to 128-row tiles

typedef __attribute__((ext_vector_type(8))) short bf16x8;
typedef __attribute__((ext_vector_type(4))) float f32x4;
typedef __attribute__((ext_vector_type(2))) int i32x2;

// ---------- bf16 helpers (manual, bit-exact) ----------
__device__ __forceinline__ float bf2f(unsigned short u) {
    return __uint_as_float(((unsigned int)u) << 16);
}
__device__ __forceinline__ unsigned short f2bf(float f) {
    unsigned int x = __float_as_uint(f);
    unsigned int lsb = (x >> 16) & 1u;
    x += 0x7fffu + lsb;  // round-to-nearest-even
    return (unsigned short)(x >> 16);
}

// ---------- flag-aware loads for harness float tensors (bf16 or fp32) ----------
__device__ __forceinline__ float ldF(const void* p, size_t i, bool bf) {
    return bf ? bf2f(((const unsigned short*)p)[i]) : ((const float*)p)[i];
}

// ---------- async global->LDS 16B copy ----------
__device__ __forceinline__ void gl2lds16(const unsigned short* g, unsigned short* l) {
    __builtin_amdgcn_global_load_lds(
        (const __attribute__((address_space(1))) void*)g,
        (__attribute__((address_space(3))) void*)l, 16, 0, 0);
}

// ---------- dtype + int64 detection (one wave, lane-parallel) ----------
__global__ void k_detect(const unsigned int* __restrict__ xw, const int* __restrict__ raw,
                         int* __restrict__ flag) {
    int lane = threadIdx.x;
    int cnt = 0, nz = 0;
    for (int i = lane; i < 256; i += 64) {
        unsigned short lo = (unsigned short)(xw[i] & 0xffffu);
        int e = (lo >> 7) & 0xff;
        if (e >= 110 && e <= 135) cnt++;
    }
    for (int i = 2 * lane + 1; i < 512; i += 128)
        if (raw[i] != 0) nz++;
#pragma unroll
    for (int off = 32; off > 0; off >>= 1) {
        cnt += __shfl_down(cnt, off);
        nz  += __shfl_down(nz, off);
    }
    if (lane == 0) {
        flag[0] = (cnt >= 128) ? 1 : 0;  // 1 = float tensors are bf16
        flag[1] = (nz == 0) ? 1 : 0;     // 1 = edge_index is raw int64
    }
}

// ---------- degree + counts (reads raw edge_index directly) ----------
__global__ void k_canon_deg(const int* __restrict__ raw, const void* __restrict__ ew,
                            const int* __restrict__ flagp,
                            float* __restrict__ deg, int* __restrict__ counts) {
    bool bf = (flagp[0] != 0);
    int is64 = flagp[1];
    int e = blockIdx.x * blockDim.x + threadIdx.x;
    if (e >= N_EDGES) return;
    int d;
    if (is64) d = raw[2 * (N_EDGES + e)];
    else      d = raw[N_EDGES + e];
    atomicAdd(&deg[d], ldF(ew, e, bf));
    atomicAdd(&counts[d], 1);
}

// ---------- pass 1: per-block count sums + fused dinv/selfnorm ----------
__global__ __launch_bounds__(256) void k_part(const int* __restrict__ counts,
                                              const float* __restrict__ deg,
                                              float* __restrict__ dinv,
                                              float* __restrict__ selfnorm,
                                              int* __restrict__ bsum) {
    __shared__ int s[256];
    int t = threadIdx.x;
    int i = blockIdx.x * 256 + t;
    int c = (i < N_NODES) ? counts[i] : 0;
    if (i < N_NODES) {
        float d = deg[i] + 1.0f;
        float r = rsqrtf(d);
        dinv[i] = r;
        selfnorm[i] = r * r;
    }
    s[t] = c;
    __syncthreads();
    for (int off = 128; off > 0; off >>= 1) {
        if (t < off) s[t] += s[t + off];
        __syncthreads();
    }
    if (t == 0) bsum[blockIdx.x] = s[0];
}

// ---------- pass 2: exclusive scan of 79 block sums (1 tiny block) ----------
__global__ void k_scanb(const int* __restrict__ bsum, int* __restrict__ bofs,
                        int* __restrict__ rowptr) {
    __shared__ int s[128];
    int t = threadIdx.x;
    int v = (t < NBLK) ? bsum[t] : 0;
    s[t] = v;
    __syncthreads();
    for (int off = 1; off < 128; off <<= 1) {
        int u = (t >= off) ? s[t - off] : 0;
        __syncthreads();
        s[t] += u;
        __syncthreads();
    }
    if (t < NBLK) bofs[t] = s[t] - v;  // exclusive
    if (t == NBLK - 1) rowptr[N_NODES] = s[t];
}

// ---------- pass 3: intra-block scan + block offset -> rowptr ----------
__global__ __launch_bounds__(256) void k_row(const int* __restrict__ counts,
                                             const int* __restrict__ bofs,
                                             int* __restrict__ rowptr) {
    __shared__ int s[256];
    int t = threadIdx.x;
    int b = blockIdx.x;
    int i = b * 256 + t;
    int c = (i < N_NODES) ? counts[i] : 0;
    s[t] = c;
    __syncthreads();
    for (int off = 1; off < 256; off <<= 1) {
        int u = (t >= off) ? s[t - off] : 0;
        __syncthreads();
        s[t] += u;
        __syncthreads();
    }
    if (i < N_NODES) rowptr[i] = bofs[b] + s[t] - c;
}

// ---------- scatter edges into CSR-by-dst: packed (src, norm) pairs ----------
__global__ void k_csr(const int* __restrict__ raw, const void* __restrict__ ew,
                      const int* __restrict__ flagp,
                      const float* __restrict__ dinv, const int* __restrict__ rowptr,
                      int* __restrict__ fill, int* __restrict__ csr_pair) {
    bool bf = (flagp[0] != 0);
    int is64 = flagp[1];
    int e = blockIdx.x * blockDim.x + threadIdx.x;
    if (e >= N_EDGES) return;
    int s, d;
    if (is64) { s = raw[2 * e]; d = raw[2 * (N_EDGES + e)]; }
    else      { s = raw[e];     d = raw[N_EDGES + e]; }
    int p = rowptr[d] + atomicAdd(&fill[d], 1);
    float nrm = dinv[s] * ldF(ew, e, bf) * dinv[d];
    i32x2 pv;
    pv.x = s;
    pv.y = __float_as_int(nrm);
    *(i32x2*)(csr_pair + 2 * (size_t)p) = pv;
}

// ---------- prep: pack weights | cast biases + W5 -> fp32 (457 blocks) ----------
__global__ __launch_bounds__(256) void k_prep(const void* __restrict__ W1,
                                              const void* __restrict__ W2,
                                              const void* __restrict__ W3,
                                              const void* __restrict__ W4,
                                              const void* __restrict__ b1,
                                              const void* __restrict__ b2,
                                              const void* __restrict__ b3,
                                              const void* __restrict__ b4,
                                              const void* __restrict__ W5,
                                              const int* __restrict__ flagp,
                                              unsigned short* __restrict__ Wp,
                                              float* __restrict__ biasf) {
    bool bf = (*flagp != 0);
    int b = blockIdx.x;
    int t = threadIdx.x;
    if (b < 448) {
        int gidx = b * 256 + t;  // < 114688 exactly
        const void* W;
        int idx = gidx, N, nbl;
        if (gidx < 32768)      { W = W1; N = 512; nbl = 5; }
        else if (gidx < 65536) { W = W2; N = 512; nbl = 5; idx -= 32768; }
        else if (gidx < 98304) { W = W3; N = 512; nbl = 5; idx -= 65536; }
        else                   { W = W4; N = 256; nbl = 4; idx -= 98304; }
        int lane = idx & 63;
        int blk = idx >> 6;
        int nb = blk & ((1 << nbl) - 1);
        int kb = blk >> nbl;
        int n = (nb << 4) + (lane & 15);
        int kbase = (kb << 5) + ((lane >> 4) << 3);
        unsigned short o[8];
#pragma unroll
        for (int j = 0; j < 8; ++j)
            o[j] = f2bf(ldF(W, (size_t)(kbase + j) * N + n, bf));
        *(uint4*)(&Wp[(size_t)gidx * 8]) = *(const uint4*)o;
    } else {
        int i = (b - 448) * 256 + t;
        if (i >= 2304) return;
        if (i < 2048) {
            int L = i >> 9, r = i & 511;
            if (L == 3 && r >= 256) return;
            const void* bb = (L == 0) ? b1 : (L == 1) ? b2 : (L == 2) ? b3 : b4;
            biasf[i] = ldF(bb, r, bf);
        } else {
            biasf[i] = ldF(W5, i - 2048, bf);  // fp32 W5 at biasf[2048..2303]
        }
    }
}

// ---------- MFMA bf16 GEMM, 64x128 tile, BK=64, XCD-pinned 1D grid ----------
// R12 postmortem: 128x128 grid (640 blocks) = 2.5 blocks/CU -> occupancy 20%,
// MfmaUtil 8%, latency-exposed staging. Halving BM doubles blocks (1280 =
// ~5/CU) and cuts LDS to 25.6 KB (6/CU cap) -> TLP hides the barrier drain.
// XCD mapping kept: 313 row-tiles, 40/XCD -> A panel 2.56 MB L2-resident
// (R12: FETCH 82->22 MB verified).
__global__ __launch_bounds__(256) void k_gemm_mfma(const unsigned short* __restrict__ Abase,
                                                   const void* __restrict__ Xraw,
                                                   const int* __restrict__ flagp,
                                                   int useX,
                                                   const unsigned short* __restrict__ Bp,
                                                   unsigned short* __restrict__ C,
                                                   int M, int K, int N) {
    const int AP = 72;  // A-tile row stride (64 + 8 pad) shorts -> 2-way-max banks
    __shared__ __align__(16) unsigned short As[64 * AP];   // 9216 B
    __shared__ __align__(16) unsigned short Bs[2 * 8 * 512];  // 16384 B
    bool bf = (*flagp != 0);
    bool cvt = useX && !bf;  // fp32 x -> convert in staging
    const unsigned short* A = useX ? (const unsigned short*)Xraw : Abase;
    const float* Af = (const float*)Xraw;

    int mt = (M + 63) >> 6;         // row tiles (313)
    int rpx = (mt + 7) >> 3;        // row tiles per XCD (40)
    int nty = N >> 7;               // col tiles (4 or 2)
    int xcd = blockIdx.x & 7;
    int t = blockIdx.x >> 3;
    int trow = t / nty;
    int ycol = t - trow * nty;
    int xrow = xcd * rpx + trow;
    if (xrow >= mt) return;
    int row0 = xrow << 6;
    int col0 = ycol << 7;

    int tid = threadIdx.x;
    int lane = tid & 63;
    int wave = tid >> 6;
    int wr = wave >> 1, wc = wave & 1;  // wave tile 32x64
    int nbt = N >> 4;
    int q = lane >> 4;
    int mm = lane & 15;

    f32x4 acc[2][4] = {};

    for (int kb2 = 0; kb2 < (K >> 6); ++kb2) {
        const unsigned short* breg0 = Bp + (((size_t)(2 * kb2) * nbt + (col0 >> 4)) << 9);
        const unsigned short* breg1 = Bp + (((size_t)(2 * kb2 + 1) * nbt + (col0 >> 4)) << 9);
        gl2lds16(breg0 + (size_t)tid * 8, &Bs[(size_t)tid * 8]);
        gl2lds16(breg0 + (size_t)(tid + 256) * 8, &Bs[(size_t)(tid + 256) * 8]);
        gl2lds16(breg1 + (size_t)tid * 8, &Bs[4096 + (size_t)tid * 8]);
        gl2lds16(breg1 + (size_t)(tid + 256) * 8, &Bs[4096 + (size_t)(tid + 256) * 8]);
        // A tile: 64 rows x 64 k = 512 x 16B chunks, 2 per thread
#pragma unroll
        for (int i = 0; i < 2; ++i) {
            int c = tid + i * 256;
            int row = c >> 3, kq = c & 7;
            int grow = min(row0 + row, M - 1);  // clamp: x is unpadded
            size_t idx = (size_t)grow * K + (kb2 << 6) + (kq << 3);
            if (!cvt) {
                uint4 v = *(const uint4*)(&A[idx]);
                *(uint4*)(&As[row * AP + (kq << 3)]) = v;
            } else {
                float4 v0 = *(const float4*)(Af + idx);
                float4 v1 = *(const float4*)(Af + idx + 4);
                uint4 o;
                o.x = (unsigned int)f2bf(v0.x) | ((unsigned int)f2bf(v0.y) << 16);
                o.y = (unsigned int)f2bf(v0.z) | ((unsigned int)f2bf(v0.w) << 16);
                o.z = (unsigned int)f2bf(v1.x) | ((unsigned int)f2bf(v1.y) << 16);
                o.w = (unsigned int)f2bf(v1.z) | ((unsigned int)f2bf(v1.w) << 16);
                *(uint4*)(&As[row * AP + (kq << 3)]) = o;
            }
        }
        __syncthreads();
#pragma unroll
        for (int kk = 0; kk < 2; ++kk) {
            bf16x8 af[2], bfr[4];
#pragma unroll
            for (int mb = 0; mb < 2; ++mb)
                af[mb] = *(const bf16x8*)(&As[(wr * 32 + mb * 16 + mm) * AP + kk * 32 + q * 8]);
#pragma unroll
            for (int nb = 0; nb < 4; ++nb)
                bfr[nb] = *(const bf16x8*)(&Bs[kk * 4096 + ((wc * 4 + nb) * 64 + lane) * 8]);
#pragma unroll
            for (int mb = 0; mb < 2; ++mb)
#pragma unroll
                for (int nb = 0; nb < 4; ++nb)
                    acc[mb][nb] = __builtin_amdgcn_mfma_f32_16x16x32_bf16(
                        af[mb], bfr[nb], acc[mb][nb], 0, 0, 0);
        }
        __syncthreads();
    }
#pragma unroll
    for (int mb = 0; mb < 2; ++mb) {
#pragma unroll
        for (int r = 0; r < 4; ++r) {
            int grow = row0 + wr * 32 + mb * 16 + q * 4 + r;
            if (grow < M) {
#pragma unroll
                for (int nb = 0; nb < 4; ++nb) {
                    int gcol = col0 + wc * 64 + nb * 16 + mm;
                    C[(size_t)grow * N + gcol] = f2bf(acc[mb][nb][r]);
                }
            }
        }
    }
}

// ---------- row-load + fma helpers for the gather ----------
template <int W>
__device__ __forceinline__ void ldrow(const unsigned short* h, size_t row, int F, int lane,
                                      unsigned int* u) {
    const unsigned int* p = (const unsigned int*)(h + row * F) + lane * W;
    if constexpr (W == 4) {
        uint4 v = *(const uint4*)p; u[0] = v.x; u[1] = v.y; u[2] = v.z; u[3] = v.w;
    } else {
        uint2 v = *(const uint2*)p; u[0] = v.x; u[1] = v.y;
    }
}
template <int W>
__device__ __forceinline__ void fmarow(const unsigned int* u, float w, float* acc) {
#pragma unroll
    for (int k = 0; k < W; ++k) {
        acc[2 * k]     = fmaf(bf2f((unsigned short)(u[k] & 0xffffu)), w, acc[2 * k]);
        acc[2 * k + 1] = fmaf(bf2f((unsigned short)(u[k] >> 16)),     w, acc[2 * k + 1]);
    }
}

// ---------- 4-chunk XCD-pinned wave-per-node aggregate (F=512) ----------
// Byte-exact round-7 winner: 42.8 us, FETCH 90 MB, delivered ~10 TB/s.
__global__ __launch_bounds__(64) void k_agg_w(const unsigned short* __restrict__ h,
                                              const int* __restrict__ rowptr,
                                              const int* __restrict__ csr_pair,
                                              const float* __restrict__ selfnorm,
                                              const float* __restrict__ biasf,
                                              unsigned short* __restrict__ out) {
    constexpr int F = 512;
    int lane = threadIdx.x;
    int chunk = blockIdx.x & 3;
    int node = blockIdx.x >> 2;
    int e0 = rowptr[node], e1 = rowptr[node + 1];
    float sn = selfnorm[node];
    const unsigned short* hb = h + chunk * 128 + lane * 2;  // this lane's dword column

    float a0, a1;
    {
        unsigned int u = *(const unsigned int*)(hb + (size_t)node * F);
        a0 = sn * bf2f((unsigned short)(u & 0xffffu));
        a1 = sn * bf2f((unsigned short)(u >> 16));
    }
    const i32x2* pairs = (const i32x2*)csr_pair;
    int j = e0;
    for (; j + 7 < e1; j += 8) {
        i32x2 p0 = pairs[j],     p1 = pairs[j + 1], p2 = pairs[j + 2], p3 = pairs[j + 3];
        i32x2 p4 = pairs[j + 4], p5 = pairs[j + 5], p6 = pairs[j + 6], p7 = pairs[j + 7];
        unsigned int u0 = *(const unsigned int*)(hb + (size_t)p0.x * F);
        unsigned int u1 = *(const unsigned int*)(hb + (size_t)p1.x * F);
        unsigned int u2 = *(const unsigned int*)(hb + (size_t)p2.x * F);
        unsigned int u3 = *(const unsigned int*)(hb + (size_t)p3.x * F);
        unsigned int u4 = *(const unsigned int*)(hb + (size_t)p4.x * F);
        unsigned int u5 = *(const unsigned int*)(hb + (size_t)p5.x * F);
        unsigned int u6 = *(const unsigned int*)(hb + (size_t)p6.x * F);
        unsigned int u7 = *(const unsigned int*)(hb + (size_t)p7.x * F);
        float w0 = __int_as_float(p0.y), w1 = __int_as_float(p1.y);
        float w2 = __int_as_float(p2.y), w3 = __int_as_float(p3.y);
        float w4 = __int_as_float(p4.y), w5 = __int_as_float(p5.y);
        float w6 = __int_as_float(p6.y), w7 = __int_as_float(p7.y);
        a0 = fmaf(bf2f((unsigned short)(u0 & 0xffffu)), w0, a0);
        a1 = fmaf(bf2f((unsigned short)(u0 >> 16)),     w0, a1);
        a0 = fmaf(bf2f((unsigned short)(u1 & 0xffffu)), w1, a0);
        a1 = fmaf(bf2f((unsigned short)(u1 >> 16)),     w1, a1);
        a0 = fmaf(bf2f((unsigned short)(u2 & 0xffffu)), w2, a0);
        a1 = fmaf(bf2f((unsigned short)(u2 >> 16)),     w2, a1);
        a0 = fmaf(bf2f((unsigned short)(u3 & 0xffffu)), w3, a0);
        a1 = fmaf(bf2f((unsigned short)(u3 >> 16)),     w3, a1);
        a0 = fmaf(bf2f((unsigned short)(u4 & 0xffffu)), w4, a0);
        a1 = fmaf(bf2f((unsigned short)(u4 >> 16)),     w4, a1);
        a0 = fmaf(bf2f((unsigned short)(u5 & 0xffffu)), w5, a0);
        a1 = fmaf(bf2f((unsigned short)(u5 >> 16)),     w5, a1);
        a0 = fmaf(bf2f((unsigned short)(u6 & 0xffffu)), w6, a0);
        a1 = fmaf(bf2f((unsigned short)(u6 >> 16)),     w6, a1);
        a0 = fmaf(bf2f((unsigned short)(u7 & 0xffffu)), w7, a0);
        a1 = fmaf(bf2f((unsigned short)(u7 >> 16)),     w7, a1);
    }
    for (; j + 3 < e1; j += 4) {
        i32x2 p0 = pairs[j], p1 = pairs[j + 1], p2 = pairs[j + 2], p3 = pairs[j + 3];
        unsigned int u0 = *(const unsigned int*)(hb + (size_t)p0.x * F);
        unsigned int u1 = *(const unsigned int*)(hb + (size_t)p1.x * F);
        unsigned int u2 = *(const unsigned int*)(hb + (size_t)p2.x * F);
        unsigned int u3 = *(const unsigned int*)(hb + (size_t)p3.x * F);
        float w0 = __int_as_float(p0.y), w1 = __int_as_float(p1.y);
        float w2 = __int_as_float(p2.y), w3 = __int_as_float(p3.y);
        a0 = fmaf(bf2f((unsigned short)(u0 & 0xffffu)), w0, a0);
        a1 = fmaf(bf2f((unsigned short)(u0 >> 16)),     w0, a1);
        a0 = fmaf(bf2f((unsigned short)(u1 & 0xffffu)), w1, a0);
        a1 = fmaf(bf2f((unsigned short)(u1 >> 16)),     w1, a1);
        a0 = fmaf(bf2f((unsigned short)(u2 & 0xffffu)), w2, a0);
        a1 = fmaf(bf2f((unsigned short)(u2 >> 16)),     w2, a1);
        a0 = fmaf(bf2f((unsigned short)(u3 & 0xffffu)), w3, a0);
        a1 = fmaf(bf2f((unsigned short)(u3 >> 16)),     w3, a1);
    }
    for (; j < e1; ++j) {
        i32x2 p0 = pairs[j];
        unsigned int u0 = *(const unsigned int*)(hb + (size_t)p0.x * F);
        float w0 = __int_as_float(p0.y);
        a0 = fmaf(bf2f((unsigned short)(u0 & 0xffffu)), w0, a0);
        a1 = fmaf(bf2f((unsigned short)(u0 >> 16)),     w0, a1);
    }
    {
        const float* bp = biasf + chunk * 128 + lane * 2;
        a0 = fmaxf(a0 + bp[0], 0.f);
        a1 = fmaxf(a1 + bp[1], 0.f);
        unsigned int o = (unsigned int)f2bf(a0) | ((unsigned int)f2bf(a1) << 16);
        *(unsigned int*)(out + (size_t)node * F + chunk * 128 + lane * 2) = o;
    }
}

// ---------- L4 agg fused with L5 GEMV: whole-row (F=256), 1-wave blocks ----------
__global__ __launch_bounds__(64) void k_agg_fuse(const unsigned short* __restrict__ h,
                                                 const int* __restrict__ rowptr,
                                                 const int* __restrict__ csr_pair,
                                                 const float* __restrict__ selfnorm,
                                                 const float* __restrict__ biasf,
                                                 const float* __restrict__ w5f,
                                                 float* __restrict__ h5) {
    constexpr int F = 256, FPL = 4, W = 2;
    int lane = threadIdx.x;
    int node = blockIdx.x;
    int e0 = rowptr[node], e1 = rowptr[node + 1];
    float sn = selfnorm[node];

    float acc[FPL];
    {
        unsigned int u[W];
        ldrow<W>(h, (size_t)node, F, lane, u);
#pragma unroll
        for (int k = 0; k < W; ++k) {
            acc[2 * k]     = sn * bf2f((unsigned short)(u[k] & 0xffffu));
            acc[2 * k + 1] = sn * bf2f((unsigned short)(u[k] >> 16));
        }
    }
    const i32x2* pairs = (const i32x2*)csr_pair;
    int j = e0;
    for (; j + 7 < e1; j += 8) {
        i32x2 p0 = pairs[j],     p1 = pairs[j + 1], p2 = pairs[j + 2], p3 = pairs[j + 3];
        i32x2 p4 = pairs[j + 4], p5 = pairs[j + 5], p6 = pairs[j + 6], p7 = pairs[j + 7];
        unsigned int u0[W], u1[W], u2[W], u3[W], u4[W], u5[W], u6[W], u7[W];
        ldrow<W>(h, (size_t)p0.x, F, lane, u0);
        ldrow<W>(h, (size_t)p1.x, F, lane, u1);
        ldrow<W>(h, (size_t)p2.x, F, lane, u2);
        ldrow<W>(h, (size_t)p3.x, F, lane, u3);
        ldrow<W>(h, (size_t)p4.x, F, lane, u4);
        ldrow<W>(h, (size_t)p5.x, F, lane, u5);
        ldrow<W>(h, (size_t)p6.x, F, lane, u6);
        ldrow<W>(h, (size_t)p7.x, F, lane, u7);
        fmarow<W>(u0, __int_as_float(p0.y), acc);
        fmarow<W>(u1, __int_as_float(p1.y), acc);
        fmarow<W>(u2, __int_as_float(p2.y), acc);
        fmarow<W>(u3, __int_as_float(p3.y), acc);
        fmarow<W>(u4, __int_as_float(p4.y), acc);
        fmarow<W>(u5, __int_as_float(p5.y), acc);
        fmarow<W>(u6, __int_as_float(p6.y), acc);
        fmarow<W>(u7, __int_as_float(p7.y), acc);
    }
    for (; j + 3 < e1; j += 4) {
        i32x2 p0 = pairs[j], p1 = pairs[j + 1], p2 = pairs[j + 2], p3 = pairs[j + 3];
        unsigned int u0[W], u1[W], u2[W], u3[W];
        ldrow<W>(h, (size_t)p0.x, F, lane, u0);
        ldrow<W>(h, (size_t)p1.x, F, lane, u1);
        ldrow<W>(h, (size_t)p2.x, F, lane, u2);
        ldrow<W>(h, (size_t)p3.x, F, lane, u3);
        fmarow<W>(u0, __int_as_float(p0.y), acc);
        fmarow<W>(u1, __int_as_float(p1.y), acc);
        fmarow<W>(u2, __int_as_float(p2.y), acc);
        fmarow<W>(u3, __int_as_float(p3.y), acc);
    }
    for (; j < e1; ++j) {
        i32x2 p0 = pairs[j];
        unsigned int u0[W];
        ldrow<W>(h, (size_t)p0.x, F, lane, u0);
        fmarow<W>(u0, __int_as_float(p0.y), acc);
    }
    const float* bp = biasf + lane * FPL;
    const float* wp = w5f + lane * FPL;
    float partial = 0.f;
#pragma unroll
    for (int k = 0; k < FPL; ++k)
        partial += fmaxf(acc[k] + bp[k], 0.f) * wp[k];
#pragma unroll
    for (int off = 32; off > 0; off >>= 1)
        partial += __shfl_xor(partial, off);
    if (lane == 0) h5[node] = partial;
}

// ---------- final scalar aggregate, write output in harness dtype ----------
__global__ void k_final(const float* __restrict__ h5, const int* __restrict__ rowptr,
                        const int* __restrict__ csr_pair,
                        const float* __restrict__ selfnorm,
                        const void* __restrict__ b5, const int* __restrict__ flagp,
                        void* __restrict__ out) {
    bool bf = (*flagp != 0);
    int i = blockIdx.x * blockDim.x + threadIdx.x;
    if (i >= N_NODES) return;
    float acc = selfnorm[i] * h5[i];
    int e0 = rowptr[i], e1 = rowptr[i + 1];
    for (int j = e0; j < e1; ++j) {
        int s = csr_pair[2 * (size_t)j];
        float w = __int_as_float(csr_pair[2 * (size_t)j + 1]);
        acc += w * h5[s];
    }
    acc += ldF(b5, 0, bf);
    if (bf) ((unsigned short*)out)[i] = f2bf(acc);
    else    ((float*)out)[i] = acc;
}

extern "C" void kernel_launch(void* const* d_in, const int* in_sizes, int n_in,
                              void* d_out, int out_size, void* d_ws, size_t ws_size,
                              hipStream_t stream) {
    const void* x  = d_in[0];
    const int*  ei = (const int*)d_in[1];
    const void* ea = d_in[2];
    const void* W1 = d_in[3];
    const void* b1 = d_in[4];
    const void* W2 = d_in[5];
    const void* b2 = d_in[6];
    const void* W3 = d_in[7];
    const void* b3 = d_in[8];
    const void* W4 = d_in[9];
    const void* b4 = d_in[10];
    const void* W5 = d_in[11];
    const void* b5 = d_in[12];

    char* ws = (char*)d_ws;
    size_t off = 0;
    auto take = [&](size_t bytes) -> void* {
        off = (off + 255) & ~(size_t)255;
        void* p = ws + off;
        off += bytes;
        return p;
    };
    int*   flagp    = (int*)take(2 * sizeof(int));
    float* deg      = (float*)take(N_NODES * sizeof(float));
    int*   counts   = (int*)take(N_NODES * sizeof(int));
    int*   fill     = (int*)take(N_NODES * sizeof(int));
    size_t zspan    = (size_t)((char*)(fill + N_NODES) - (char*)deg);
    float* dinv     = (float*)take(N_NODES * sizeof(float));
    float* selfnorm = (float*)take(N_NODES * sizeof(float));
    float* h5       = (float*)take(N_NODES * sizeof(float));
    float* biasf    = (float*)take(2304 * sizeof(float));  // 4x512 biases + 256 W5
    int*   bsum     = (int*)take(128 * sizeof(int));
    int*   bofs     = (int*)take(128 * sizeof(int));
    int*   rowptr   = (int*)take((N_NODES + 1) * sizeof(int));
    int*   csr_pair = (int*)take((size_t)N_EDGES * 2 * sizeof(int));  // (src, normbits)
    unsigned short* Wp = (unsigned short*)take((size_t)114688 * 8 * sizeof(unsigned short));
    unsigned short* P  = (unsigned short*)take((size_t)MPAD * 512 * sizeof(unsigned short));
    unsigned short* H  = (unsigned short*)take((size_t)MPAD * 512 * sizeof(unsigned short));

    (void)hipMemsetAsync(deg, 0, zspan, stream);

    const int EB = (N_EDGES + 255) / 256;
    const int NB = (N_NODES + 255) / 256;  // 79 == NBLK
    const int AGW = N_NODES * 4;  // 4 chunks per node (R7 winner)

    k_detect<<<1, 64, 0, stream>>>((const unsigned int*)x, ei, flagp);
    k_canon_deg<<<EB, 256, 0, stream>>>(ei, ea, flagp, deg, counts);
    k_part<<<NB, 256, 0, stream>>>(counts, deg, dinv, selfnorm, bsum);
    k_scanb<<<1, 128, 0, stream>>>(bsum, bofs, rowptr);
    k_row<<<NB, 256, 0, stream>>>(counts, bofs, rowptr);
    k_csr<<<EB, 256, 0, stream>>>(ei, ea, flagp, dinv, rowptr, fill, csr_pair);

    k_prep<<<457, 256, 0, stream>>>(W1, W2, W3, W4, b1, b2, b3, b4, W5, flagp,
                                    Wp, biasf);

    const int MT64 = (N_NODES + 63) / 64;   // 313 row tiles
    const int RPX = (MT64 + 7) / 8;         // 40 row tiles per XCD
    const int G512 = 8 * RPX * 4;           // 1280 blocks (N=512)
    const int G256 = 8 * RPX * 2;           // 640 blocks (N=256)

    k_gemm_mfma<<<G512, 256, 0, stream>>>(P, x, flagp, 1,
                                          Wp, H, N_NODES, 512, 512);
    k_agg_w<<<AGW, 64, 0, stream>>>(H, rowptr, csr_pair, selfnorm, biasf, P);
    k_gemm_mfma<<<G512, 256, 0, stream>>>(P, x, flagp, 0,
                                          Wp + (size_t)32768 * 8, H,
                                          N_NODES, 512, 512);
    k_agg_w<<<AGW, 64, 0, stream>>>(H, rowptr, csr_pair, selfnorm, biasf + 512, P);
    k_gemm_mfma<<<G512, 256, 0, stream>>>(P, x, flagp, 0,
                                          Wp + (size_t)65536 * 8, H,
                                          N_NODES, 512, 512);
    k_agg_w<<<AGW, 64, 0, stream>>>(H, rowptr, csr_pair, selfnorm, biasf + 1024, P);
    k_gemm_mfma<<<G256, 256, 0, stream>>>(P, x, flagp, 0,
                                          Wp + (size_t)98304 * 8, H,
                                          N_NODES, 512, 256);
    k_agg_fuse<<<N_NODES, 64, 0, stream>>>(H, rowptr, csr_pair, selfnorm,
                                           biasf + 1536, biasf + 2048, h5);

    k_final<<<NB, 256, 0, stream>>>(h5, rowptr, csr_pair, selfnorm, b5, flagp,
                                    d_out);
}